// Round 14
// baseline (903.023 us; speedup 1.0000x reference)
//
#include <hip/hip_runtime.h>
#include <hip/hip_bf16.h>
#include <hip/hip_cooperative_groups.h>
#include <math.h>

namespace cg = cooperative_groups;

#define NEGV -1000000000.0f

static constexpr int B_ = 16, N_ = 128, BN_ = 2048;
static constexpr int E_ = 384, V_ = 8000;

typedef __attribute__((ext_vector_type(8))) short short8v;
typedef __attribute__((ext_vector_type(4))) float f32x4;

// ---------------- helpers ----------------
__device__ inline float wave_sum(float v) {
#pragma unroll
  for (int o = 32; o; o >>= 1) v += __shfl_xor(v, o);
  return v;
}
__device__ inline float wave_max(float v) {
#pragma unroll
  for (int o = 32; o; o >>= 1) v = fmaxf(v, __shfl_xor(v, o));
  return v;
}
__device__ inline float fast_tanh(float x) {
  return 1.f - 2.f / (1.f + __expf(2.f * x));
}
__device__ inline float fast_tanh_pre(float x2) {
  return 1.f - 2.f / (1.f + __expf(x2));
}
__device__ inline float fast_sig(float x) {
  return 1.f / (1.f + __expf(-x));
}
__device__ __forceinline__ void gl16(const void* g, void* l) {
  __builtin_amdgcn_global_load_lds((const __attribute__((address_space(1))) void*)g,
                                   (__attribute__((address_space(3))) void*)l, 16, 0, 0);
}

// ---------------- multi-segment fp32 -> bf16 cast ----------------
struct CastArgs {
  const float* s[6];
  unsigned long long d[6];
  int base[6];
  int total;
  int special;
};
__device__ inline void cast_body(const CastArgs& a, int gsize, int gid0) {
  const int nq = a.total >> 2;
  for (int q = gid0; q < nq; q += gsize) {
    const int e = q << 2;
    int k = 5;
    while (e < a.base[k]) --k;
    const int i = e - a.base[k];
    __hip_bfloat16* dst = (__hip_bfloat16*)a.d[k] + i;
    if (k == a.special) {
      const int row = i >> 9, col = i & 511;
      const float* sp = a.s[k] + (size_t)row * 513 + col;
#pragma unroll
      for (int u = 0; u < 4; ++u) dst[u] = __float2bfloat16(sp[u]);
    } else {
      float4 v = *(const float4*)(a.s[k] + i);
      __hip_bfloat16 h0 = __float2bfloat16(v.x), h1 = __float2bfloat16(v.y);
      __hip_bfloat16 h2 = __float2bfloat16(v.z), h3 = __float2bfloat16(v.w);
      ushort4 u4 = {*(unsigned short*)&h0, *(unsigned short*)&h1,
                    *(unsigned short*)&h2, *(unsigned short*)&h3};
      *(ushort4*)dst = u4;
    }
  }
}

// ---------------- prologue: embed + hbuf sentinel-memset + cast1 ----------------
__global__ __launch_bounds__(256) void prologue_kernel(
    const int* __restrict__ ids, const float* __restrict__ emb,
    __hip_bfloat16* __restrict__ xb, __hip_bfloat16* __restrict__ hbuf,
    CastArgs c1) {
  const int bid = blockIdx.x, tid = threadIdx.x;
  if (bid < 256) {
    for (int row = bid; row < 2048; row += 256) {
      const int id = ids[row];
      for (int e = tid; e < E_; e += 256)
        xb[(size_t)row * E_ + e] = __float2bfloat16(emb[(size_t)id * E_ + e]);
    }
  } else if (bid < 288) {
    const unsigned total = 3u * 128u * 8192u * 2u;
    const float pf = __builtin_bit_cast(float, 0x7f7f7f7fu);
    f32x4 pat = {pf, pf, pf, pf};
    char* base = (char*)hbuf;
    for (unsigned off = (unsigned)((bid - 256) * 256 + tid) * 16u; off < total;
         off += 32u * 256u * 16u) {
      asm volatile("global_store_dwordx4 %0, %1, %2 sc0 sc1"
                   :: "v"(off), "v"(pat), "s"(base) : "memory");
    }
  } else {
    cast_body(c1, 256 * 256, (bid - 288) * 256 + tid);
  }
}

// ---------------- 128x128-tile bf16 MFMA GEMM body ----------------
// MASK: 0 none, 1 int cmask. OUT: 0 normal, 3 xprojT layout.
template <int ACT, int MASK, int OUT>
__device__ __forceinline__ void gemm128_impl(
    const __hip_bfloat16* A, int lda, const __hip_bfloat16* W, int ldw,
    const float* bias, float* C, int ldc, __hip_bfloat16* Cb, int ldcb,
    int N, int K, const int* maskp, int ldm, int m0, int n0,
    char* smA, char* smB) {
  const int tid = threadIdx.x;
  const int wid = tid >> 6, lane = tid & 63;
  const int nkt = K >> 5;
  const int rm = (wid >> 1) << 6, rn = (wid & 1) << 6;
  const int lrow = lane & 15, kq = lane >> 4;
  const int fs = ((lrow >> 1) & 3) << 4;

  f32x4 acc[4][4];
#pragma unroll
  for (int i = 0; i < 4; ++i)
#pragma unroll
    for (int j = 0; j < 4; ++j) acc[i][j] = {0.f, 0.f, 0.f, 0.f};

  auto stage = [&](int bi, int kt) {
#pragma unroll
    for (int c = 0; c < 2; ++c) {
      const int p = ((c * 4 + wid) << 6) + lane;
      const int row = p >> 2, cb = (p & 3) << 4;
      const int sw = ((row >> 1) & 3) << 4;
      const unsigned loff = (unsigned)__builtin_amdgcn_readfirstlane((c * 4 + wid) << 10);
      {
        const char* src = (const char*)A + ((size_t)(m0 + row) * lda + (size_t)kt * 32) * 2 + (cb ^ sw);
        gl16(src, smA + bi * 8192 + loff);
      }
      {
        int gr = n0 + row;
        if (gr >= N) gr = N - 1;
        const char* src = (const char*)W + ((size_t)gr * ldw + (size_t)kt * 32) * 2 + (cb ^ sw);
        gl16(src, smB + bi * 8192 + loff);
      }
    }
  };
  auto compute = [&](int bi) {
    const char* Ab = smA + bi * 8192;
    const char* Bb = smB + bi * 8192;
    const int roff = (kq << 4) ^ fs;
    short8v a[4], b[4];
#pragma unroll
    for (int i = 0; i < 4; ++i)
      a[i] = *(const short8v*)(Ab + (rm + i * 16 + lrow) * 64 + roff);
#pragma unroll
    for (int j = 0; j < 4; ++j)
      b[j] = *(const short8v*)(Bb + (rn + j * 16 + lrow) * 64 + roff);
#pragma unroll
    for (int i = 0; i < 4; ++i)
#pragma unroll
      for (int j = 0; j < 4; ++j)
        acc[i][j] = __builtin_amdgcn_mfma_f32_16x16x32_bf16(a[i], b[j], acc[i][j], 0, 0, 0);
  };

  stage(0, 0);
  for (int kt = 0; kt < nkt; ++kt) {
    __syncthreads();
    if (kt + 1 < nkt) stage((kt + 1) & 1, kt + 1);
    compute(kt & 1);
  }

#pragma unroll
  for (int i = 0; i < 4; ++i) {
#pragma unroll
    for (int r = 0; r < 4; ++r) {
      const int m = m0 + rm + i * 16 + kq * 4 + r;
#pragma unroll
      for (int j = 0; j < 4; ++j) {
        const int n = n0 + rn + j * 16 + lrow;
        if (n < N) {
          float v = acc[i][j][r] + (bias ? bias[n] : 0.f);
          if (ACT == 1) v = fast_tanh(v);
          if (MASK == 1) {
            if (maskp[(size_t)m * ldm + n] == 0) v = NEGV;
          }
          if (OUT == 3) {
            const size_t idx = (((size_t)(m & 127) * 32 + ((n >> 4) & 31)) * 4 +
                               (n >> 9)) * 256 + (((size_t)(m >> 7)) << 4) + (n & 15);
            Cb[idx] = __float2bfloat16(v);
          } else {
            if (C) C[(size_t)m * ldc + n] = v;
            if (Cb) Cb[(size_t)m * ldcb + n] = __float2bfloat16(v);
          }
        }
      }
    }
  }
}

// ---------------- 64x64-tile bf16 MFMA GEMM body ----------------
__device__ __forceinline__ void gemm64_impl(
    const __hip_bfloat16* A, int lda, const __hip_bfloat16* W, int ldw,
    const float* bias, const float* bias2,
    float* C, int ldc, float* C2, __hip_bfloat16* Cb, int ldcb,
    int K, int act, int trout, int m0, int n0, char* AlB, char* BlB) {
  const int tid = threadIdx.x;
  const int wid = tid >> 6, lane = tid & 63;
  const int nkt = K >> 5;
  const int rm = (wid >> 1) << 5, rn = (wid & 1) << 5;
  const int lrow = lane & 15, kq = lane >> 4;
  const int fs = ((lrow >> 1) & 3) << 4;

  f32x4 acc[2][2];
#pragma unroll
  for (int i = 0; i < 2; ++i)
#pragma unroll
    for (int j = 0; j < 2; ++j) acc[i][j] = {0.f, 0.f, 0.f, 0.f};

  auto stage = [&](int bi, int kt) {
    const int row = tid >> 2, cb = (tid & 3) << 4;
    const int sw = ((row >> 1) & 3) << 4;
    const unsigned loff = (unsigned)__builtin_amdgcn_readfirstlane(wid << 10);
    {
      const char* src = (const char*)A + ((size_t)(m0 + row) * lda + (size_t)kt * 32) * 2 + (cb ^ sw);
      gl16(src, AlB + bi * 4096 + loff);
    }
    {
      const char* src = (const char*)W + ((size_t)(n0 + row) * ldw + (size_t)kt * 32) * 2 + (cb ^ sw);
      gl16(src, BlB + bi * 4096 + loff);
    }
  };
  auto compute = [&](int bi) {
    const char* Ab = AlB + bi * 4096;
    const char* Bb = BlB + bi * 4096;
    const int roff = (kq << 4) ^ fs;
    short8v a[2], b[2];
#pragma unroll
    for (int i = 0; i < 2; ++i)
      a[i] = *(const short8v*)(Ab + (rm + i * 16 + lrow) * 64 + roff);
#pragma unroll
    for (int j = 0; j < 2; ++j)
      b[j] = *(const short8v*)(Bb + (rn + j * 16 + lrow) * 64 + roff);
#pragma unroll
    for (int i = 0; i < 2; ++i)
#pragma unroll
      for (int j = 0; j < 2; ++j)
        acc[i][j] = __builtin_amdgcn_mfma_f32_16x16x32_bf16(a[i], b[j], acc[i][j], 0, 0, 0);
  };

  stage(0, 0);
  for (int kt = 0; kt < nkt; ++kt) {
    __syncthreads();
    if (kt + 1 < nkt) stage((kt + 1) & 1, kt + 1);
    compute(kt & 1);
  }

#pragma unroll
  for (int i = 0; i < 2; ++i) {
#pragma unroll
    for (int r = 0; r < 4; ++r) {
      const int m = m0 + rm + i * 16 + kq * 4 + r;
#pragma unroll
      for (int j = 0; j < 2; ++j) {
        const int n = n0 + rn + j * 16 + lrow;
        float v = acc[i][j][r];
        if (trout == 2) {
          if (n < 512) {
            C[(size_t)m * ldc + n] = fast_tanh(v + bias[n]);
          } else {
            C2[(size_t)m * 128 + (n - 512)] = v + bias2[n - 512];
          }
        } else {
          if (act == 2) v *= 2.f;
          else {
            v += (bias ? bias[n] : 0.f);
            if (act == 1) v = fast_tanh(v);
          }
          if (trout == 1) {
            Cb[(((size_t)(m >> 7) * 512 + n) << 7) + (m & 127)] = __float2bfloat16(v);
          } else {
            if (C) C[(size_t)m * ldc + n] = v;
            if (Cb) Cb[(size_t)m * ldcb + n] = __float2bfloat16(v);
          }
        }
      }
    }
  }
}

// ---------------- xproj: z-batched 128-tile GEMM -> xprojT layout ----------------
__global__ __launch_bounds__(256) void xproj_kernel(
    const __hip_bfloat16* __restrict__ A, const __hip_bfloat16* __restrict__ Wih,
    const float* __restrict__ b0, const float* __restrict__ b1,
    const float* __restrict__ b2, __hip_bfloat16* __restrict__ xpT) {
  __shared__ __align__(16) char smA[16384], smB[16384];
  const int z = blockIdx.z;
  const float* bias = (z == 0) ? b0 : (z == 1 ? b1 : b2);
  gemm128_impl<0, 0, 3>(A, E_, Wih + (size_t)z * 2048 * 384, E_, bias,
                        nullptr, 0, xpT + (size_t)z * 2048 * 2048, 0,
                        2048, E_, nullptr, 0, blockIdx.y * 128,
                        blockIdx.x * 128, smA, smB);
}

// ---------------- standalone vocab kernel (R11-proven pattern) ----------------
__global__ __launch_bounds__(256) void vocab_kernel(
    const __hip_bfloat16* __restrict__ combb, const __hip_bfloat16* __restrict__ vocw,
    const float* __restrict__ vocab_b, float* __restrict__ out1,
    const int* __restrict__ cmask) {
  __shared__ __align__(16) char smA[16384], smB[16384];
  const int bid = blockIdx.x;
  const int bx = bid % 63, by = bid / 63;
  gemm128_impl<0, 1, 0>(combb, 512, vocw, 512, vocab_b, out1, V_, nullptr, 0,
                        V_, 512, cmask, V_, by * 128, bx * 128, smA, smB);
}

// ---------------- FUSED: lstm (96 blocks) + cast2 (64 blocks) ----------------
__global__ __launch_bounds__(256) void fused_kernel(
    const __hip_bfloat16* __restrict__ xpT,    // [3][t][g][gate][b][d]
    const float* __restrict__ whhF, const float* __restrict__ whhB,
    const float* __restrict__ whhD,
    __hip_bfloat16* __restrict__ hbuf,
    __hip_bfloat16* __restrict__ ehsb, __hip_bfloat16* __restrict__ ehsT,
    __hip_bfloat16* __restrict__ catb,
    CastArgs ca2) {
  extern __shared__ char sm[];
  const int bid = blockIdx.x;
  const int tid = threadIdx.x;

  if (bid >= 96) {  // ---- cast2 role ----
    cast_body(ca2, 64 * 256, (bid - 96) * 256 + tid);
    return;
  }

  // ---- LSTM role ----
  const int l = bid >> 5, g = bid & 31;
  const int lane = tid & 63, wid = tid >> 6;
  char* smW = sm;                                   // 65536
  char* smH = sm + 65536;                           // 16384
  __hip_bfloat16* hout = (__hip_bfloat16*)(sm + 65536 + 16384);  // 512
  char* hist = sm + 65536 + 16384 + 512;            // 65536

  const float* wsrc = (l == 0) ? whhF : ((l == 1) ? whhB : whhD);
  auto cv = [](float x) -> unsigned {
    __hip_bfloat16 h = __float2bfloat16(x);
    return (unsigned)*(unsigned short*)&h;
  };
  for (int p = tid; p < 4096; p += 256) {
    const int r = p >> 6, cb = (p & 63) << 4;
    const int grow = (r & 3) * 512 + (g << 4) + (r >> 2);
    const float* srcp = wsrc + (size_t)grow * 512 + ((p & 63) << 3);
    float4 u0 = *(const float4*)srcp;
    float4 u1 = *(const float4*)(srcp + 4);
    uint4 q;
    q.x = cv(u0.x) | (cv(u0.y) << 16);
    q.y = cv(u0.z) | (cv(u0.w) << 16);
    q.z = cv(u1.x) | (cv(u1.y) << 16);
    q.w = cv(u1.z) | (cv(u1.w) << 16);
    *(uint4*)(smW + r * 1024 + (cb ^ ((r & 7) << 4))) = q;
  }

  const int lrow = lane & 15, kq = lane >> 4;
  const int swz = (lrow & 7) << 4;
  const char* aB = smW + (wid * 16 + lrow) * 1024;
  const char* bB = smH + lrow * 1024;
  const int dl16 = wid * 4 + kq;
  const int dg = (g << 4) + dl16;
  const int bb = lrow;
  const bool rev = (l == 1);
  const __hip_bfloat16* xl = xpT + (size_t)l * 2048 * 2048;
  __hip_bfloat16* hb_l = hbuf + (size_t)l * 128 * 8192;
  const int gq = tid >> 3;
  const int b0 = (tid & 7) * 2;
  const int gb = gq * 32;
  const int sw0 = (b0 & 7) << 4, sw1 = ((b0 + 1) & 7) << 4;
  float c = 0.f;

  for (int s = 0; s < 128; ++s) {
    const int t = rev ? 127 - s : s;
    const __hip_bfloat16* xt = xl + (size_t)t * 32768 + (g << 10) + (bb << 4) + dl16;
    const float xgi = __bfloat162float(xt[0]);
    const float xgf = __bfloat162float(xt[256]);
    const float xgg = __bfloat162float(xt[512]);
    const float xgo = __bfloat162float(xt[768]);

    if (s > 0) {
      if (gq != g) {
        const char* hsrc = (const char*)(hb_l + (size_t)(s - 1) * 8192);
        const unsigned loff = (unsigned)(tid * 64);
        unsigned hv;
        while (true) {
          asm volatile(
              "global_load_ushort %0, %1, %2 sc0 sc1\n\t"
              "s_waitcnt vmcnt(0)"
              : "=&v"(hv) : "v"(loff), "s"(hsrc) : "memory");
          if ((hv & 0xffffu) != 0x7f7fu) break;
          __builtin_amdgcn_s_sleep(1);
        }
        f32x4 q0, q1, q2, q3;
        asm volatile(
            "global_load_dwordx4 %0, %4, %5 sc0 sc1\n\t"
            "global_load_dwordx4 %1, %4, %5 offset:16 sc0 sc1\n\t"
            "global_load_dwordx4 %2, %4, %5 offset:32 sc0 sc1\n\t"
            "global_load_dwordx4 %3, %4, %5 offset:48 sc0 sc1\n\t"
            "s_waitcnt vmcnt(0)"
            : "=&v"(q0), "=&v"(q1), "=&v"(q2), "=&v"(q3)
            : "v"(loff), "s"(hsrc) : "memory");
        *(f32x4*)(smH + b0 * 1024 + (gb ^ sw0)) = q0;
        *(f32x4*)(smH + b0 * 1024 + ((gb + 16) ^ sw0)) = q1;
        *(f32x4*)(smH + (b0 + 1) * 1024 + (gb ^ sw1)) = q2;
        *(f32x4*)(smH + (b0 + 1) * 1024 + ((gb + 16) ^ sw1)) = q3;
      } else {
        const char* hl = (const char*)hout + b0 * 32;
        f32x4 c0 = *(const f32x4*)(hl);
        f32x4 c1 = *(const f32x4*)(hl + 16);
        f32x4 c2 = *(const f32x4*)(hl + 32);
        f32x4 c3 = *(const f32x4*)(hl + 48);
        *(f32x4*)(smH + b0 * 1024 + (gb ^ sw0)) = c0;
        *(f32x4*)(smH + b0 * 1024 + ((gb + 16) ^ sw0)) = c1;
        *(f32x4*)(smH + (b0 + 1) * 1024 + (gb ^ sw1)) = c2;
        *(f32x4*)(smH + (b0 + 1) * 1024 + ((gb + 16) ^ sw1)) = c3;
      }
    } else {
      const f32x4 z = {0.f, 0.f, 0.f, 0.f};
      *(f32x4*)(smH + b0 * 1024 + (gb ^ sw0)) = z;
      *(f32x4*)(smH + b0 * 1024 + ((gb + 16) ^ sw0)) = z;
      *(f32x4*)(smH + (b0 + 1) * 1024 + (gb ^ sw1)) = z;
      *(f32x4*)(smH + (b0 + 1) * 1024 + ((gb + 16) ^ sw1)) = z;
    }
    __syncthreads();  // A

    f32x4 acc0 = {0.f, 0.f, 0.f, 0.f}, acc1 = {0.f, 0.f, 0.f, 0.f};
#pragma unroll
    for (int kt = 0; kt < 16; kt += 2) {
      const int off0 = ((kt * 64 + (kq << 4)) ^ swz);
      const int off1 = (((kt + 1) * 64 + (kq << 4)) ^ swz);
      short8v a0 = *(const short8v*)(aB + off0);
      short8v b0v = *(const short8v*)(bB + off0);
      short8v a1 = *(const short8v*)(aB + off1);
      short8v b1v = *(const short8v*)(bB + off1);
      acc0 = __builtin_amdgcn_mfma_f32_16x16x32_bf16(a0, b0v, acc0, 0, 0, 0);
      acc1 = __builtin_amdgcn_mfma_f32_16x16x32_bf16(a1, b1v, acc1, 0, 0, 0);
    }
    const f32x4 acc = acc0 + acc1;

    const float gi = acc[0] + xgi;
    const float gf = acc[1] + xgf;
    const float gg = acc[2] + xgg;
    const float go = acc[3] + xgo;
    c = fmaf(fast_sig(gf), c, fast_sig(gi) * fast_tanh(gg));
    const float h = fast_sig(go) * fast_tanh(c);
    __hip_bfloat16 hb16 = __float2bfloat16(h);
    const unsigned short hraw = *(unsigned short*)&hb16;
    hout[bb * 16 + dl16] = hb16;
    *(unsigned short*)(hist + s * 512 + (bb * 16 + dl16) * 2) = hraw;
    __syncthreads();  // B

    if (s < 127 && wid == (s & 3) && (lane < 32)) {
      f32x4 hv4 = *(const f32x4*)((const char*)hout + lane * 16);
      char* hdst = (char*)(hb_l + (size_t)s * 8192);
      asm volatile("global_store_dwordx4 %0, %1, %2 sc0 sc1"
                   :: "v"((unsigned)((g << 9) + lane * 16)), "v"(hv4), "s"(hdst)
                   : "memory");
    }
  }

  // ---- epilogue: write own slice of ehsb/ehsT/catb from LDS history ----
  __syncthreads();
  const int bb2 = tid >> 4, lo2 = tid & 15;
  if (l < 2) {
    const int hoff = (bb2 * 16 + lo2) * 2;
    char* dstT = (char*)(ehsT + ((size_t)bb2 * 1024 + l * 512 + (g << 4) + lo2) * 128);
    for (int tc = 0; tc < 128; tc += 32) {
      unsigned v[16];
#pragma unroll
      for (int w = 0; w < 16; ++w) {
        const int t0 = tc + 2 * w;
        const int s0 = rev ? 127 - t0 : t0;
        const int s1 = rev ? 126 - t0 : t0 + 1;
        unsigned a = *(const unsigned short*)(hist + s0 * 512 + hoff);
        unsigned b2 = *(const unsigned short*)(hist + s1 * 512 + hoff);
        v[w] = a | (b2 << 16);
      }
#pragma unroll
      for (int q = 0; q < 4; ++q)
        *(uint4*)(dstT + tc * 2 + q * 16) =
            make_uint4(v[q * 4], v[q * 4 + 1], v[q * 4 + 2], v[q * 4 + 3]);
    }
    for (int k = 0; k < 8; ++k) {
      const int t = lo2 * 8 + k;
      const int s0 = rev ? 127 - t : t;
      const char* srcp = hist + s0 * 512 + bb2 * 32;
      uint4 ra = *(const uint4*)srcp;
      uint4 rb = *(const uint4*)(srcp + 16);
      char* dp = (char*)(ehsb + ((size_t)(bb2 * 128 + t)) * 1024 + l * 512 + (g << 4));
      *(uint4*)dp = ra;
      *(uint4*)(dp + 16) = rb;
    }
  } else {
    for (int k = 0; k < 8; ++k) {
      const int t = lo2 * 8 + k;
      const char* srcp = hist + t * 512 + bb2 * 32;
      uint4 ra = *(const uint4*)srcp;
      uint4 rb = *(const uint4*)(srcp + 16);
      char* dp = (char*)(catb + ((size_t)(bb2 * 128 + t)) * 1536 + (g << 4));
      *(uint4*)dp = ra;
      *(uint4*)(dp + 16) = rb;
    }
  }
}

// ---------------- cooperative tail (NO vocab) ----------------
struct CoopArgs {
  const __hip_bfloat16 *catb, *ehsb, *w1, *w2, *ehsT, *combw, *wgw;
  __hip_bfloat16 *catbw, *etT, *alphab, *combb;
  const float *v_att, *comb_b, *Wg_b, *ptr_b, *ptr_W, *ps_W, *ps_b;
  const int* src_mask;
  float *dterm, *wgout, *baseb, *out0;
};

__device__ void score_body(const CoopArgs& a, int bid, int tid, char* smbuf) {
  const int b = bid >> 5, tg = bid & 31;
  const int t0 = tg * 4;
  float (*dt)[512] = (float(*)[512])smbuf;
  float* vs = (float*)(smbuf + 8192);
  float (*red)[4][128] = (float(*)[4][128])(smbuf + 10240);
  float (*al)[128] = (float(*)[128])(smbuf + 18432);
  for (int i = tid; i < 2048; i += 256)
    dt[i >> 9][i & 511] = a.dterm[((size_t)(b * 128 + t0 + (i >> 9))) * 512 + (i & 511)];
  vs[tid] = a.v_att[tid];
  vs[tid + 256] = a.v_att[256 + tid];
  __syncthreads();
  const int n0 = (tid & 63) << 1, ah = tid >> 6;
  {
    const __hip_bfloat16* ep = a.etT + (((size_t)b * 512 + ah * 128) << 7) + n0;
    const float* vp = vs + ah * 128;
    const float* dp0 = &dt[0][ah * 128];
    const float* dp1 = &dt[1][ah * 128];
    const float* dp2 = &dt[2][ah * 128];
    const float* dp3 = &dt[3][ah * 128];
    float p00 = 0, p01 = 0, p10 = 0, p11 = 0, p20 = 0, p21 = 0, p30 = 0, p31 = 0;
    for (int q = 0; q < 128; ++q) {
      const unsigned u = *(const unsigned*)(ep + ((size_t)q << 7));
      unsigned u0 = u << 16, u1 = u & 0xffff0000u;
      const float e0 = __builtin_bit_cast(float, u0);
      const float e1 = __builtin_bit_cast(float, u1);
      const float va = vp[q];
      p00 = fmaf(va, fast_tanh_pre(dp0[q] + e0), p00);
      p01 = fmaf(va, fast_tanh_pre(dp0[q] + e1), p01);
      p10 = fmaf(va, fast_tanh_pre(dp1[q] + e0), p10);
      p11 = fmaf(va, fast_tanh_pre(dp1[q] + e1), p11);
      p20 = fmaf(va, fast_tanh_pre(dp2[q] + e0), p20);
      p21 = fmaf(va, fast_tanh_pre(dp2[q] + e1), p21);
      p30 = fmaf(va, fast_tanh_pre(dp3[q] + e0), p30);
      p31 = fmaf(va, fast_tanh_pre(dp3[q] + e1), p31);
    }
    red[0][ah][n0] = p00; red[0][ah][n0 + 1] = p01;
    red[1][ah][n0] = p10; red[1][ah][n0 + 1] = p11;
    red[2][ah][n0] = p20; red[2][ah][n0 + 1] = p21;
    red[3][ah][n0] = p30; red[3][ah][n0 + 1] = p31;
  }
  __syncthreads();
#pragma unroll
  for (int tp = 0; tp < 2; ++tp) {
    const int tt = tp * 2 + (tid >> 7);
    const int n = tid & 127;
    float sc = red[tt][0][n] + red[tt][1][n] + red[tt][2][n] + red[tt][3][n];
    if (a.src_mask[b * 128 + n] == 0) sc = NEGV;
    al[tt][n] = sc;
  }
  __syncthreads();
  {
    const int tt = tid >> 6, lane = tid & 63;
    const float v0 = al[tt][lane], v1 = al[tt][lane + 64];
    const float m = wave_max(fmaxf(v0, v1));
    const float e0 = __expf(v0 - m), e1 = __expf(v1 - m);
    const float inv = 1.f / wave_sum(e0 + e1);
    __hip_bfloat16* ap = a.alphab + ((size_t)(b * 128 + t0 + tt)) * 128;
    ap[lane] = __float2bfloat16(e0 * inv);
    ap[lane + 64] = __float2bfloat16(e1 * inv);
  }
}

__device__ void pointer_body(const CoopArgs& a, int bt, int tid, char* smbuf) {
  const int b = bt >> 7, t = bt & 127;
  float* r0 = (float*)smbuf;
  float* r1 = r0 + 4;
  float* r2 = r0 + 8;
  float* fin = r0 + 12;
  float off_p = 0.f, diag_p = 0.f, sent_p;
  if (tid < 128) {
    const float ba = a.baseb[(size_t)bt * 128 + tid];
    const float pw = a.ps_W[tid];
    off_p = tanhf(ba) * pw;
    diag_p = tanhf(ba + a.ptr_W[tid * 513 + 512]) * pw;
  }
  sent_p = a.wgout[(size_t)bt * 512 + tid] + a.wgout[(size_t)bt * 512 + 256 + tid];
  off_p = wave_sum(off_p);
  diag_p = wave_sum(diag_p);
  sent_p = wave_sum(sent_p);
  const int wid = tid >> 6, lane = tid & 63;
  if (lane == 0) { r0[wid] = off_p; r1[wid] = diag_p; r2[wid] = sent_p; }
  __syncthreads();
  if (tid == 0) {
    const float psb = a.ps_b[0];
    fin[0] = r0[0] + r0[1] + r0[2] + r0[3] + psb;
    fin[1] = r1[0] + r1[1] + r1[2] + r1[3] + psb;
    fin[2] = r2[0] + r2[1] + r2[2] + r2[3];
  }
  __syncthreads();
  const float s_off = fin[0], s_diag = fin[1], sent = fin[2];
  if (tid < 129) {
    float v;
    if (tid == 128) v = sent;
    else {
      v = (tid == t) ? s_diag : s_off;
      if (a.src_mask[b * 128 + tid] == 0) v = NEGV;
    }
    a.out0[(size_t)bt * 129 + tid] = v;
  }
  __syncthreads();
}

__global__ __launch_bounds__(256) void coop_kernel(CoopArgs a) {
  __shared__ __align__(16) char smbuf[40960];
  cg::grid_group grid = cg::this_grid();
  const int bid = blockIdx.x, tid = threadIdx.x;

  // P1: dterm (x2 prescale) + etT (x2, transposed)
  if (bid < 256) {
    gemm64_impl(a.catb, 1536, a.w1, 512, nullptr, nullptr, a.dterm, 512,
                nullptr, nullptr, 0, 512, 2, 0, (bid >> 3) * 64, (bid & 7) * 64,
                smbuf, smbuf + 8192);
  } else {
    const int l = bid - 256;
    gemm64_impl(a.ehsb, 1024, a.w2, 1024, nullptr, nullptr, nullptr, 0,
                nullptr, a.etT, 0, 1024, 2, 1, (l >> 3) * 64, (l & 7) * 64,
                smbuf, smbuf + 8192);
  }
  grid.sync();

  // P2: score + softmax
  score_body(a, bid, tid, smbuf);
  grid.sync();

  // P3: context
  {
    const int z = bid >> 5, r = bid & 31;
    gemm64_impl(a.alphab + (size_t)z * 128 * 128, 128,
                a.ehsT + (size_t)z * 1024 * 128, 128, nullptr, nullptr,
                nullptr, 0, nullptr, a.catbw + 512 + (size_t)z * 128 * 1536,
                1536, 128, 0, 0, (r >> 4) * 64, (r & 15) * 64,
                smbuf, smbuf + 8192);
  }
  grid.sync();

  // P4: combined
  if (bid < 256) {
    gemm64_impl(a.catb, 1536, a.combw, 1536, a.comb_b, nullptr, nullptr, 0,
                nullptr, a.combb, 512, 1536, 1, 0, (bid >> 3) * 64,
                (bid & 7) * 64, smbuf, smbuf + 8192);
  }
  grid.sync();

  // P5: wg/base only (vocab is a standalone post-kernel; one tile per block)
  if (bid < 320) {
    gemm64_impl(a.combb, 512, a.wgw, 512, a.Wg_b, a.ptr_b, a.wgout, 512,
                a.baseb, nullptr, 0, 512, 0, 2, (bid / 10) * 64,
                (bid % 10) * 64, smbuf, smbuf + 8192);
  }
  grid.sync();

  // P6: pointer head
  for (int bt = bid; bt < 2048; bt += 512) pointer_body(a, bt, tid, smbuf);
}

// ---------------- launch ----------------
extern "C" void kernel_launch(void* const* d_in, const int* in_sizes, int n_in,
                              void* d_out, int out_size, void* d_ws, size_t ws_size,
                              hipStream_t stream) {
  const int* src_ids   = (const int*)d_in[0];
  const int* src_mask  = (const int*)d_in[1];
  const int* cmask     = (const int*)d_in[2];
  const float* emb     = (const float*)d_in[3];
  const float* Wih_f   = (const float*)d_in[4];
  const float* Whh_f   = (const float*)d_in[5];
  const float* b_f     = (const float*)d_in[6];
  const float* Wih_b   = (const float*)d_in[7];
  const float* Whh_b   = (const float*)d_in[8];
  const float* b_b     = (const float*)d_in[9];
  const float* Wih_d   = (const float*)d_in[10];
  const float* Whh_d   = (const float*)d_in[11];
  const float* b_d     = (const float*)d_in[12];
  const float* W1      = (const float*)d_in[13];
  const float* W2      = (const float*)d_in[14];
  const float* v_att   = (const float*)d_in[15];
  const float* comb_W  = (const float*)d_in[16];
  const float* comb_b  = (const float*)d_in[17];
  const float* vocab_W = (const float*)d_in[18];
  const float* vocab_b = (const float*)d_in[19];
  const float* Wg_W    = (const float*)d_in[20];
  const float* Wg_b    = (const float*)d_in[21];
  const float* ptr_W   = (const float*)d_in[22];
  const float* ptr_b   = (const float*)d_in[23];
  const float* ps_W    = (const float*)d_in[24];
  const float* ps_b    = (const float*)d_in[25];
  (void)in_sizes; (void)n_in; (void)out_size; (void)ws_size;

  char* wsb = (char*)d_ws;
  size_t o = 0;
  auto alloc = [&](size_t bytes) { char* p = wsb + o; o = (o + bytes + 255) & ~(size_t)255; return p; };
  __hip_bfloat16* xb      = (__hip_bfloat16*)alloc((size_t)BN_ * E_ * 2);
  __hip_bfloat16* xpT     = (__hip_bfloat16*)alloc((size_t)3 * BN_ * 2048 * 2);
  __hip_bfloat16* ehsb    = (__hip_bfloat16*)alloc((size_t)BN_ * 1024 * 2);
  __hip_bfloat16* ehsT    = (__hip_bfloat16*)alloc((size_t)16 * 1024 * 128 * 2);
  __hip_bfloat16* catb    = (__hip_bfloat16*)alloc((size_t)BN_ * 1536 * 2);
  float* dterm            = (float*)alloc((size_t)BN_ * 512 * 4);
  __hip_bfloat16* etT     = (__hip_bfloat16*)alloc((size_t)16 * 512 * 128 * 2);
  __hip_bfloat16* alphab  = (__hip_bfloat16*)alloc((size_t)BN_ * 128 * 2);
  __hip_bfloat16* combb   = (__hip_bfloat16*)alloc((size_t)BN_ * 512 * 2);
  float* wgout            = (float*)alloc((size_t)BN_ * 512 * 4);
  float* baseb            = (float*)alloc((size_t)BN_ * 128 * 4);
  __hip_bfloat16* hbuf    = (__hip_bfloat16*)alloc((size_t)3 * 128 * 8192 * 2);
  __hip_bfloat16* wih16   = (__hip_bfloat16*)alloc((size_t)3 * 2048 * 384 * 2);
  __hip_bfloat16* w1_16   = (__hip_bfloat16*)alloc((size_t)512 * 512 * 2);
  __hip_bfloat16* w2_16   = (__hip_bfloat16*)alloc((size_t)512 * 1024 * 2);
  __hip_bfloat16* combw16 = (__hip_bfloat16*)alloc((size_t)512 * 1536 * 2);
  __hip_bfloat16* vocw16  = (__hip_bfloat16*)alloc((size_t)8000 * 512 * 2);
  __hip_bfloat16* wgw16   = (__hip_bfloat16*)alloc((size_t)512 * 512 * 2);
  __hip_bfloat16* ptrw16  = (__hip_bfloat16*)alloc((size_t)128 * 512 * 2);

  float* out0 = (float*)d_out;
  float* out1 = out0 + (size_t)BN_ * 129;

  CastArgs c1;
  {
    const float* s3[3] = {Wih_f, Wih_b, Wih_d};
    int acc = 0;
    for (int k = 0; k < 3; ++k) {
      c1.s[k] = s3[k];
      c1.d[k] = (unsigned long long)(wih16 + (size_t)k * 2048 * 384);
      c1.base[k] = acc;
      acc += 2048 * 384;
    }
    for (int k = 3; k < 6; ++k) { c1.s[k] = nullptr; c1.d[k] = 0; c1.base[k] = 0x7fffffff; }
    c1.total = acc; c1.special = -1;
  }
  CastArgs c2;
  {
    const float* s6[6] = {W1, W2, comb_W, vocab_W, Wg_W, ptr_W};
    __hip_bfloat16* d6[6] = {w1_16, w2_16, combw16, vocw16, wgw16, ptrw16};
    int ns[6] = {512 * 512, 512 * 1024, 512 * 1536, 8000 * 512, 512 * 512, 128 * 512};
    int acc = 0;
    for (int k = 0; k < 6; ++k) {
      c2.s[k] = s6[k]; c2.d[k] = (unsigned long long)d6[k]; c2.base[k] = acc;
      acc += ns[k];
    }
    c2.total = acc; c2.special = 5;
  }

  // 1) prologue: embed + hbuf sentinel memset + cast1
  prologue_kernel<<<544, 256, 0, stream>>>(src_ids, emb, xb, hbuf, c1);

  // 2) xproj -> xprojT layout
  xproj_kernel<<<dim3(16, 16, 3), 256, 0, stream>>>(xb, wih16, b_f, b_b, b_d, xpT);

  // 3) fused lstm + cast2
  hipError_t e1 = hipFuncSetAttribute((const void*)fused_kernel,
                      hipFuncAttributeMaxDynamicSharedMemorySize, 147968);
  (void)e1;
  fused_kernel<<<160, 256, 147968, stream>>>(
      xpT, Whh_f, Whh_b, Whh_d, hbuf, ehsb, ehsT, catb, c2);

  // 4) cooperative tail (qk -> score -> ctx -> comb -> wg/base -> pointer)
  CoopArgs ca;
  ca.catb = catb; ca.ehsb = ehsb; ca.w1 = w1_16; ca.w2 = w2_16; ca.ehsT = ehsT;
  ca.combw = combw16; ca.wgw = wgw16;
  ca.catbw = catb; ca.etT = etT; ca.alphab = alphab; ca.combb = combb;
  ca.v_att = v_att; ca.comb_b = comb_b; ca.Wg_b = Wg_b;
  ca.ptr_b = ptr_b; ca.ptr_W = ptr_W; ca.ps_W = ps_W; ca.ps_b = ps_b;
  ca.src_mask = src_mask;
  ca.dterm = dterm; ca.wgout = wgout; ca.baseb = baseb; ca.out0 = out0;
  void* kargs[] = {&ca};
  hipError_t e2 = hipLaunchCooperativeKernel((const void*)coop_kernel,
                                             dim3(512), dim3(256), kargs, 0, stream);
  (void)e2;

  // 5) vocab logits + cmask (standalone, R11-proven pattern)
  vocab_kernel<<<1008, 256, 0, stream>>>(combb, vocw16, vocab_b, out1, cmask);
}

// Round 15
// 614.432 us; speedup vs baseline: 1.4697x; 1.4697x over previous
//
#include <hip/hip_runtime.h>
#include <hip/hip_bf16.h>
#include <math.h>

#define NEGV -1000000000.0f

static constexpr int B_ = 16, N_ = 128, BN_ = 2048;
static constexpr int E_ = 384, V_ = 8000;

typedef __attribute__((ext_vector_type(8))) short short8v;
typedef __attribute__((ext_vector_type(4))) float f32x4;

// ---------------- helpers ----------------
__device__ inline float wave_sum(float v) {
#pragma unroll
  for (int o = 32; o; o >>= 1) v += __shfl_xor(v, o);
  return v;
}
__device__ inline float wave_max(float v) {
#pragma unroll
  for (int o = 32; o; o >>= 1) v = fmaxf(v, __shfl_xor(v, o));
  return v;
}
__device__ inline float fast_tanh(float x) {
  return 1.f - 2.f / (1.f + __expf(2.f * x));
}
__device__ inline float fast_tanh_pre(float x2) {
  return 1.f - 2.f / (1.f + __expf(x2));
}
__device__ inline float fast_sig(float x) {
  return 1.f / (1.f + __expf(-x));
}
__device__ __forceinline__ void gl16(const void* g, void* l) {
  __builtin_amdgcn_global_load_lds((const __attribute__((address_space(1))) void*)g,
                                   (__attribute__((address_space(3))) void*)l, 16, 0, 0);
}

// ---------------- multi-segment fp32 -> bf16 cast ----------------
struct CastArgs {
  const float* s[6];
  unsigned long long d[6];
  int base[6];
  int total;
  int special;
};
__device__ inline void cast_body(const CastArgs& a, int gsize, int gid0) {
  const int nq = a.total >> 2;
  for (int q = gid0; q < nq; q += gsize) {
    const int e = q << 2;
    int k = 5;
    while (e < a.base[k]) --k;
    const int i = e - a.base[k];
    __hip_bfloat16* dst = (__hip_bfloat16*)a.d[k] + i;
    if (k == a.special) {
      const int row = i >> 9, col = i & 511;
      const float* sp = a.s[k] + (size_t)row * 513 + col;
#pragma unroll
      for (int u = 0; u < 4; ++u) dst[u] = __float2bfloat16(sp[u]);
    } else {
      float4 v = *(const float4*)(a.s[k] + i);
      __hip_bfloat16 h0 = __float2bfloat16(v.x), h1 = __float2bfloat16(v.y);
      __hip_bfloat16 h2 = __float2bfloat16(v.z), h3 = __float2bfloat16(v.w);
      ushort4 u4 = {*(unsigned short*)&h0, *(unsigned short*)&h1,
                    *(unsigned short*)&h2, *(unsigned short*)&h3};
      *(ushort4*)dst = u4;
    }
  }
}

// ---------------- prologue: embed + hbuf sentinel-memset + cast1 ----------------
__global__ __launch_bounds__(256) void prologue_kernel(
    const int* __restrict__ ids, const float* __restrict__ emb,
    __hip_bfloat16* __restrict__ xb, __hip_bfloat16* __restrict__ hbuf,
    CastArgs c1) {
  const int bid = blockIdx.x, tid = threadIdx.x;
  if (bid < 256) {
    for (int row = bid; row < 2048; row += 256) {
      const int id = ids[row];
      for (int e = tid; e < E_; e += 256)
        xb[(size_t)row * E_ + e] = __float2bfloat16(emb[(size_t)id * E_ + e]);
    }
  } else if (bid < 288) {
    const unsigned total = 3u * 128u * 8192u * 2u;
    const float pf = __builtin_bit_cast(float, 0x7f7f7f7fu);
    f32x4 pat = {pf, pf, pf, pf};
    char* base = (char*)hbuf;
    for (unsigned off = (unsigned)((bid - 256) * 256 + tid) * 16u; off < total;
         off += 32u * 256u * 16u) {
      asm volatile("global_store_dwordx4 %0, %1, %2 sc0 sc1"
                   :: "v"(off), "v"(pat), "s"(base) : "memory");
    }
  } else {
    cast_body(c1, 256 * 256, (bid - 288) * 256 + tid);
  }
}

// ---------------- 128x128-tile bf16 MFMA GEMM body ----------------
// MASK: 0 none, 1 int cmask. OUT: 0 normal, 3 xprojT layout.
template <int ACT, int MASK, int OUT>
__device__ __forceinline__ void gemm128_impl(
    const __hip_bfloat16* A, int lda, const __hip_bfloat16* W, int ldw,
    const float* bias, float* C, int ldc, __hip_bfloat16* Cb, int ldcb,
    int N, int K, const int* maskp, int ldm, int m0, int n0,
    char* smA, char* smB) {
  const int tid = threadIdx.x;
  const int wid = tid >> 6, lane = tid & 63;
  const int nkt = K >> 5;
  const int rm = (wid >> 1) << 6, rn = (wid & 1) << 6;
  const int lrow = lane & 15, kq = lane >> 4;
  const int fs = ((lrow >> 1) & 3) << 4;

  f32x4 acc[4][4];
#pragma unroll
  for (int i = 0; i < 4; ++i)
#pragma unroll
    for (int j = 0; j < 4; ++j) acc[i][j] = {0.f, 0.f, 0.f, 0.f};

  auto stage = [&](int bi, int kt) {
#pragma unroll
    for (int c = 0; c < 2; ++c) {
      const int p = ((c * 4 + wid) << 6) + lane;
      const int row = p >> 2, cb = (p & 3) << 4;
      const int sw = ((row >> 1) & 3) << 4;
      const unsigned loff = (unsigned)__builtin_amdgcn_readfirstlane((c * 4 + wid) << 10);
      {
        const char* src = (const char*)A + ((size_t)(m0 + row) * lda + (size_t)kt * 32) * 2 + (cb ^ sw);
        gl16(src, smA + bi * 8192 + loff);
      }
      {
        int gr = n0 + row;
        if (gr >= N) gr = N - 1;
        const char* src = (const char*)W + ((size_t)gr * ldw + (size_t)kt * 32) * 2 + (cb ^ sw);
        gl16(src, smB + bi * 8192 + loff);
      }
    }
  };
  auto compute = [&](int bi) {
    const char* Ab = smA + bi * 8192;
    const char* Bb = smB + bi * 8192;
    const int roff = (kq << 4) ^ fs;
    short8v a[4], b[4];
#pragma unroll
    for (int i = 0; i < 4; ++i)
      a[i] = *(const short8v*)(Ab + (rm + i * 16 + lrow) * 64 + roff);
#pragma unroll
    for (int j = 0; j < 4; ++j)
      b[j] = *(const short8v*)(Bb + (rn + j * 16 + lrow) * 64 + roff);
#pragma unroll
    for (int i = 0; i < 4; ++i)
#pragma unroll
      for (int j = 0; j < 4; ++j)
        acc[i][j] = __builtin_amdgcn_mfma_f32_16x16x32_bf16(a[i], b[j], acc[i][j], 0, 0, 0);
  };

  stage(0, 0);
  for (int kt = 0; kt < nkt; ++kt) {
    __syncthreads();
    if (kt + 1 < nkt) stage((kt + 1) & 1, kt + 1);
    compute(kt & 1);
  }

#pragma unroll
  for (int i = 0; i < 4; ++i) {
#pragma unroll
    for (int r = 0; r < 4; ++r) {
      const int m = m0 + rm + i * 16 + kq * 4 + r;
#pragma unroll
      for (int j = 0; j < 4; ++j) {
        const int n = n0 + rn + j * 16 + lrow;
        if (n < N) {
          float v = acc[i][j][r] + (bias ? bias[n] : 0.f);
          if (ACT == 1) v = fast_tanh(v);
          if (MASK == 1) {
            if (maskp[(size_t)m * ldm + n] == 0) v = NEGV;
          }
          if (OUT == 3) {
            const size_t idx = (((size_t)(m & 127) * 32 + ((n >> 4) & 31)) * 4 +
                               (n >> 9)) * 256 + (((size_t)(m >> 7)) << 4) + (n & 15);
            Cb[idx] = __float2bfloat16(v);
          } else {
            if (C) C[(size_t)m * ldc + n] = v;
            if (Cb) Cb[(size_t)m * ldcb + n] = __float2bfloat16(v);
          }
        }
      }
    }
  }
}

// ---------------- 64x64-tile bf16 MFMA GEMM body ----------------
__device__ __forceinline__ void gemm64_impl(
    const __hip_bfloat16* A, int lda, const __hip_bfloat16* W, int ldw,
    const float* bias, const float* bias2,
    float* C, int ldc, float* C2, __hip_bfloat16* Cb, int ldcb,
    int K, int act, int trout, int m0, int n0, char* AlB, char* BlB) {
  const int tid = threadIdx.x;
  const int wid = tid >> 6, lane = tid & 63;
  const int nkt = K >> 5;
  const int rm = (wid >> 1) << 5, rn = (wid & 1) << 5;
  const int lrow = lane & 15, kq = lane >> 4;
  const int fs = ((lrow >> 1) & 3) << 4;

  f32x4 acc[2][2];
#pragma unroll
  for (int i = 0; i < 2; ++i)
#pragma unroll
    for (int j = 0; j < 2; ++j) acc[i][j] = {0.f, 0.f, 0.f, 0.f};

  auto stage = [&](int bi, int kt) {
    const int row = tid >> 2, cb = (tid & 3) << 4;
    const int sw = ((row >> 1) & 3) << 4;
    const unsigned loff = (unsigned)__builtin_amdgcn_readfirstlane(wid << 10);
    {
      const char* src = (const char*)A + ((size_t)(m0 + row) * lda + (size_t)kt * 32) * 2 + (cb ^ sw);
      gl16(src, AlB + bi * 4096 + loff);
    }
    {
      const char* src = (const char*)W + ((size_t)(n0 + row) * ldw + (size_t)kt * 32) * 2 + (cb ^ sw);
      gl16(src, BlB + bi * 4096 + loff);
    }
  };
  auto compute = [&](int bi) {
    const char* Ab = AlB + bi * 4096;
    const char* Bb = BlB + bi * 4096;
    const int roff = (kq << 4) ^ fs;
    short8v a[2], b[2];
#pragma unroll
    for (int i = 0; i < 2; ++i)
      a[i] = *(const short8v*)(Ab + (rm + i * 16 + lrow) * 64 + roff);
#pragma unroll
    for (int j = 0; j < 2; ++j)
      b[j] = *(const short8v*)(Bb + (rn + j * 16 + lrow) * 64 + roff);
#pragma unroll
    for (int i = 0; i < 2; ++i)
#pragma unroll
      for (int j = 0; j < 2; ++j)
        acc[i][j] = __builtin_amdgcn_mfma_f32_16x16x32_bf16(a[i], b[j], acc[i][j], 0, 0, 0);
  };

  stage(0, 0);
  for (int kt = 0; kt < nkt; ++kt) {
    __syncthreads();
    if (kt + 1 < nkt) stage((kt + 1) & 1, kt + 1);
    compute(kt & 1);
  }

#pragma unroll
  for (int i = 0; i < 2; ++i) {
#pragma unroll
    for (int r = 0; r < 4; ++r) {
      const int m = m0 + rm + i * 16 + kq * 4 + r;
#pragma unroll
      for (int j = 0; j < 2; ++j) {
        const int n = n0 + rn + j * 16 + lrow;
        float v = acc[i][j][r];
        if (trout == 2) {
          if (n < 512) {
            C[(size_t)m * ldc + n] = fast_tanh(v + bias[n]);
          } else {
            C2[(size_t)m * 128 + (n - 512)] = v + bias2[n - 512];
          }
        } else {
          if (act == 2) v *= 2.f;
          else {
            v += (bias ? bias[n] : 0.f);
            if (act == 1) v = fast_tanh(v);
          }
          if (trout == 1) {
            Cb[(((size_t)(m >> 7) * 512 + n) << 7) + (m & 127)] = __float2bfloat16(v);
          } else {
            if (C) C[(size_t)m * ldc + n] = v;
            if (Cb) Cb[(size_t)m * ldcb + n] = __float2bfloat16(v);
          }
        }
      }
    }
  }
}

// ---------------- xproj: z-batched 128-tile GEMM -> xprojT layout ----------------
__global__ __launch_bounds__(256) void xproj_kernel(
    const __hip_bfloat16* __restrict__ A, const __hip_bfloat16* __restrict__ Wih,
    const float* __restrict__ b0, const float* __restrict__ b1,
    const float* __restrict__ b2, __hip_bfloat16* __restrict__ xpT) {
  __shared__ __align__(16) char smA[16384], smB[16384];
  const int z = blockIdx.z;
  const float* bias = (z == 0) ? b0 : (z == 1 ? b1 : b2);
  gemm128_impl<0, 0, 3>(A, E_, Wih + (size_t)z * 2048 * 384, E_, bias,
                        nullptr, 0, xpT + (size_t)z * 2048 * 2048, 0,
                        2048, E_, nullptr, 0, blockIdx.y * 128,
                        blockIdx.x * 128, smA, smB);
}

// ---------------- FUSED: lstm (96 blocks) + cast2 (64 blocks) ----------------
__global__ __launch_bounds__(256) void fused_kernel(
    const __hip_bfloat16* __restrict__ xpT,    // [3][t][g][gate][b][d]
    const float* __restrict__ whhF, const float* __restrict__ whhB,
    const float* __restrict__ whhD,
    __hip_bfloat16* __restrict__ hbuf,
    __hip_bfloat16* __restrict__ ehsb, __hip_bfloat16* __restrict__ ehsT,
    __hip_bfloat16* __restrict__ catb,
    CastArgs ca2) {
  extern __shared__ char sm[];
  const int bid = blockIdx.x;
  const int tid = threadIdx.x;

  if (bid >= 96) {  // ---- cast2 role ----
    cast_body(ca2, 64 * 256, (bid - 96) * 256 + tid);
    return;
  }

  // ---- LSTM role ----
  const int l = bid >> 5, g = bid & 31;
  const int lane = tid & 63, wid = tid >> 6;
  char* smW = sm;                                   // 65536
  char* smH = sm + 65536;                           // 16384
  __hip_bfloat16* hout = (__hip_bfloat16*)(sm + 65536 + 16384);  // 512
  char* hist = sm + 65536 + 16384 + 512;            // 65536

  const float* wsrc = (l == 0) ? whhF : ((l == 1) ? whhB : whhD);
  auto cv = [](float x) -> unsigned {
    __hip_bfloat16 h = __float2bfloat16(x);
    return (unsigned)*(unsigned short*)&h;
  };
  for (int p = tid; p < 4096; p += 256) {
    const int r = p >> 6, cb = (p & 63) << 4;
    const int grow = (r & 3) * 512 + (g << 4) + (r >> 2);
    const float* srcp = wsrc + (size_t)grow * 512 + ((p & 63) << 3);
    float4 u0 = *(const float4*)srcp;
    float4 u1 = *(const float4*)(srcp + 4);
    uint4 q;
    q.x = cv(u0.x) | (cv(u0.y) << 16);
    q.y = cv(u0.z) | (cv(u0.w) << 16);
    q.z = cv(u1.x) | (cv(u1.y) << 16);
    q.w = cv(u1.z) | (cv(u1.w) << 16);
    *(uint4*)(smW + r * 1024 + (cb ^ ((r & 7) << 4))) = q;
  }

  const int lrow = lane & 15, kq = lane >> 4;
  const int swz = (lrow & 7) << 4;
  const char* aB = smW + (wid * 16 + lrow) * 1024;
  const char* bB = smH + lrow * 1024;
  const int dl16 = wid * 4 + kq;
  const int dg = (g << 4) + dl16;
  const int bb = lrow;
  const bool rev = (l == 1);
  const __hip_bfloat16* xl = xpT + (size_t)l * 2048 * 2048;
  __hip_bfloat16* hb_l = hbuf + (size_t)l * 128 * 8192;
  const int gq = tid >> 3;
  const int b0 = (tid & 7) * 2;
  const int gb = gq * 32;
  const int sw0 = (b0 & 7) << 4, sw1 = ((b0 + 1) & 7) << 4;
  float c = 0.f;

  for (int s = 0; s < 128; ++s) {
    const int t = rev ? 127 - s : s;
    const __hip_bfloat16* xt = xl + (size_t)t * 32768 + (g << 10) + (bb << 4) + dl16;
    const float xgi = __bfloat162float(xt[0]);
    const float xgf = __bfloat162float(xt[256]);
    const float xgg = __bfloat162float(xt[512]);
    const float xgo = __bfloat162float(xt[768]);

    if (s > 0) {
      if (gq != g) {
        const char* hsrc = (const char*)(hb_l + (size_t)(s - 1) * 8192);
        const unsigned loff = (unsigned)(tid * 64);
        unsigned hv;
        while (true) {
          asm volatile(
              "global_load_ushort %0, %1, %2 sc0 sc1\n\t"
              "s_waitcnt vmcnt(0)"
              : "=&v"(hv) : "v"(loff), "s"(hsrc) : "memory");
          if ((hv & 0xffffu) != 0x7f7fu) break;
          __builtin_amdgcn_s_sleep(1);
        }
        f32x4 q0, q1, q2, q3;
        asm volatile(
            "global_load_dwordx4 %0, %4, %5 sc0 sc1\n\t"
            "global_load_dwordx4 %1, %4, %5 offset:16 sc0 sc1\n\t"
            "global_load_dwordx4 %2, %4, %5 offset:32 sc0 sc1\n\t"
            "global_load_dwordx4 %3, %4, %5 offset:48 sc0 sc1\n\t"
            "s_waitcnt vmcnt(0)"
            : "=&v"(q0), "=&v"(q1), "=&v"(q2), "=&v"(q3)
            : "v"(loff), "s"(hsrc) : "memory");
        *(f32x4*)(smH + b0 * 1024 + (gb ^ sw0)) = q0;
        *(f32x4*)(smH + b0 * 1024 + ((gb + 16) ^ sw0)) = q1;
        *(f32x4*)(smH + (b0 + 1) * 1024 + (gb ^ sw1)) = q2;
        *(f32x4*)(smH + (b0 + 1) * 1024 + ((gb + 16) ^ sw1)) = q3;
      } else {
        const char* hl = (const char*)hout + b0 * 32;
        f32x4 c0 = *(const f32x4*)(hl);
        f32x4 c1 = *(const f32x4*)(hl + 16);
        f32x4 c2 = *(const f32x4*)(hl + 32);
        f32x4 c3 = *(const f32x4*)(hl + 48);
        *(f32x4*)(smH + b0 * 1024 + (gb ^ sw0)) = c0;
        *(f32x4*)(smH + b0 * 1024 + ((gb + 16) ^ sw0)) = c1;
        *(f32x4*)(smH + (b0 + 1) * 1024 + (gb ^ sw1)) = c2;
        *(f32x4*)(smH + (b0 + 1) * 1024 + ((gb + 16) ^ sw1)) = c3;
      }
    } else {
      const f32x4 z = {0.f, 0.f, 0.f, 0.f};
      *(f32x4*)(smH + b0 * 1024 + (gb ^ sw0)) = z;
      *(f32x4*)(smH + b0 * 1024 + ((gb + 16) ^ sw0)) = z;
      *(f32x4*)(smH + (b0 + 1) * 1024 + (gb ^ sw1)) = z;
      *(f32x4*)(smH + (b0 + 1) * 1024 + ((gb + 16) ^ sw1)) = z;
    }
    __syncthreads();  // A

    f32x4 acc0 = {0.f, 0.f, 0.f, 0.f}, acc1 = {0.f, 0.f, 0.f, 0.f};
#pragma unroll
    for (int kt = 0; kt < 16; kt += 2) {
      const int off0 = ((kt * 64 + (kq << 4)) ^ swz);
      const int off1 = (((kt + 1) * 64 + (kq << 4)) ^ swz);
      short8v a0 = *(const short8v*)(aB + off0);
      short8v b0v = *(const short8v*)(bB + off0);
      short8v a1 = *(const short8v*)(aB + off1);
      short8v b1v = *(const short8v*)(bB + off1);
      acc0 = __builtin_amdgcn_mfma_f32_16x16x32_bf16(a0, b0v, acc0, 0, 0, 0);
      acc1 = __builtin_amdgcn_mfma_f32_16x16x32_bf16(a1, b1v, acc1, 0, 0, 0);
    }
    const f32x4 acc = acc0 + acc1;

    const float gi = acc[0] + xgi;
    const float gf = acc[1] + xgf;
    const float gg = acc[2] + xgg;
    const float go = acc[3] + xgo;
    c = fmaf(fast_sig(gf), c, fast_sig(gi) * fast_tanh(gg));
    const float h = fast_sig(go) * fast_tanh(c);
    __hip_bfloat16 hb16 = __float2bfloat16(h);
    const unsigned short hraw = *(unsigned short*)&hb16;
    hout[bb * 16 + dl16] = hb16;
    *(unsigned short*)(hist + s * 512 + (bb * 16 + dl16) * 2) = hraw;
    __syncthreads();  // B

    if (s < 127 && wid == (s & 3) && (lane < 32)) {
      f32x4 hv4 = *(const f32x4*)((const char*)hout + lane * 16);
      char* hdst = (char*)(hb_l + (size_t)s * 8192);
      asm volatile("global_store_dwordx4 %0, %1, %2 sc0 sc1"
                   :: "v"((unsigned)((g << 9) + lane * 16)), "v"(hv4), "s"(hdst)
                   : "memory");
    }
  }

  // ---- epilogue: write own slice of ehsb/ehsT/catb from LDS history ----
  __syncthreads();
  const int bb2 = tid >> 4, lo2 = tid & 15;
  if (l < 2) {
    const int hoff = (bb2 * 16 + lo2) * 2;
    char* dstT = (char*)(ehsT + ((size_t)bb2 * 1024 + l * 512 + (g << 4) + lo2) * 128);
    for (int tc = 0; tc < 128; tc += 32) {
      unsigned v[16];
#pragma unroll
      for (int w = 0; w < 16; ++w) {
        const int t0 = tc + 2 * w;
        const int s0 = rev ? 127 - t0 : t0;
        const int s1 = rev ? 126 - t0 : t0 + 1;
        unsigned a = *(const unsigned short*)(hist + s0 * 512 + hoff);
        unsigned b2 = *(const unsigned short*)(hist + s1 * 512 + hoff);
        v[w] = a | (b2 << 16);
      }
#pragma unroll
      for (int q = 0; q < 4; ++q)
        *(uint4*)(dstT + tc * 2 + q * 16) =
            make_uint4(v[q * 4], v[q * 4 + 1], v[q * 4 + 2], v[q * 4 + 3]);
    }
    for (int k = 0; k < 8; ++k) {
      const int t = lo2 * 8 + k;
      const int s0 = rev ? 127 - t : t;
      const char* srcp = hist + s0 * 512 + bb2 * 32;
      uint4 ra = *(const uint4*)srcp;
      uint4 rb = *(const uint4*)(srcp + 16);
      char* dp = (char*)(ehsb + ((size_t)(bb2 * 128 + t)) * 1024 + l * 512 + (g << 4));
      *(uint4*)dp = ra;
      *(uint4*)(dp + 16) = rb;
    }
  } else {
    for (int k = 0; k < 8; ++k) {
      const int t = lo2 * 8 + k;
      const char* srcp = hist + t * 512 + bb2 * 32;
      uint4 ra = *(const uint4*)srcp;
      uint4 rb = *(const uint4*)(srcp + 16);
      char* dp = (char*)(catb + ((size_t)(bb2 * 128 + t)) * 1536 + (g << 4));
      *(uint4*)dp = ra;
      *(uint4*)(dp + 16) = rb;
    }
  }
}

// ---------------- qk: dterm + etT merged (R11-proven) ----------------
__global__ __launch_bounds__(256) void qk_kernel(
    const __hip_bfloat16* __restrict__ catb, const __hip_bfloat16* __restrict__ ehsb,
    const __hip_bfloat16* __restrict__ w1, const __hip_bfloat16* __restrict__ w2,
    float* __restrict__ dterm, __hip_bfloat16* __restrict__ etT) {
  __shared__ __align__(16) char AlB[8192], BlB[8192];
  const int bid = blockIdx.x;
  if (bid < 256) {
    const int bx = bid & 7, by = bid >> 3;
    gemm64_impl(catb, 1536, w1, 512, nullptr, nullptr, dterm, 512, nullptr,
                nullptr, 0, 512, 2, 0, by * 64, bx * 64, AlB, BlB);
  } else {
    const int l = bid - 256;
    const int bx = l & 7, by = l >> 3;
    gemm64_impl(ehsb, 1024, w2, 1024, nullptr, nullptr, nullptr, 0, nullptr,
                etT, 0, 1024, 2, 1, by * 64, bx * 64, AlB, BlB);
  }
}

// ---------------- score + softmax -> alpha; 4 t's per block (R11) ----------------
__global__ __launch_bounds__(256) void score_kernel(
    const float* __restrict__ dterm, const __hip_bfloat16* __restrict__ etT,
    const float* __restrict__ v_att, const int* __restrict__ src_mask,
    __hip_bfloat16* __restrict__ alphab) {
  const int b = blockIdx.x >> 5, tg = blockIdx.x & 31;
  const int t0 = tg * 4;
  const int tid = threadIdx.x;
  __shared__ float dt[4][512], vs[512], red[4][4][128], al[4][128];
  for (int i = tid; i < 2048; i += 256)
    dt[i >> 9][i & 511] = dterm[((size_t)(b * 128 + t0 + (i >> 9))) * 512 + (i & 511)];
  vs[tid] = v_att[tid];
  vs[tid + 256] = v_att[256 + tid];
  __syncthreads();
  const int n0 = (tid & 63) << 1, ah = tid >> 6;
  {
    const __hip_bfloat16* ep = etT + (((size_t)b * 512 + ah * 128) << 7) + n0;
    const float* vp = vs + ah * 128;
    const float* dp0 = &dt[0][ah * 128];
    const float* dp1 = &dt[1][ah * 128];
    const float* dp2 = &dt[2][ah * 128];
    const float* dp3 = &dt[3][ah * 128];
    float p00 = 0, p01 = 0, p10 = 0, p11 = 0, p20 = 0, p21 = 0, p30 = 0, p31 = 0;
    for (int q = 0; q < 128; ++q) {
      const unsigned u = *(const unsigned*)(ep + ((size_t)q << 7));
      unsigned u0 = u << 16, u1 = u & 0xffff0000u;
      const float e0 = __builtin_bit_cast(float, u0);
      const float e1 = __builtin_bit_cast(float, u1);
      const float va = vp[q];
      p00 = fmaf(va, fast_tanh_pre(dp0[q] + e0), p00);
      p01 = fmaf(va, fast_tanh_pre(dp0[q] + e1), p01);
      p10 = fmaf(va, fast_tanh_pre(dp1[q] + e0), p10);
      p11 = fmaf(va, fast_tanh_pre(dp1[q] + e1), p11);
      p20 = fmaf(va, fast_tanh_pre(dp2[q] + e0), p20);
      p21 = fmaf(va, fast_tanh_pre(dp2[q] + e1), p21);
      p30 = fmaf(va, fast_tanh_pre(dp3[q] + e0), p30);
      p31 = fmaf(va, fast_tanh_pre(dp3[q] + e1), p31);
    }
    red[0][ah][n0] = p00; red[0][ah][n0 + 1] = p01;
    red[1][ah][n0] = p10; red[1][ah][n0 + 1] = p11;
    red[2][ah][n0] = p20; red[2][ah][n0 + 1] = p21;
    red[3][ah][n0] = p30; red[3][ah][n0 + 1] = p31;
  }
  __syncthreads();
#pragma unroll
  for (int tp = 0; tp < 2; ++tp) {
    const int tt = tp * 2 + (tid >> 7);
    const int n = tid & 127;
    float sc = red[tt][0][n] + red[tt][1][n] + red[tt][2][n] + red[tt][3][n];
    if (src_mask[b * 128 + n] == 0) sc = NEGV;
    al[tt][n] = sc;
  }
  __syncthreads();
  {
    const int tt = tid >> 6, lane = tid & 63;
    const float v0 = al[tt][lane], v1 = al[tt][lane + 64];
    const float m = wave_max(fmaxf(v0, v1));
    const float e0 = __expf(v0 - m), e1 = __expf(v1 - m);
    const float inv = 1.f / wave_sum(e0 + e1);
    __hip_bfloat16* ap = alphab + ((size_t)(b * 128 + t0 + tt)) * 128;
    ap[lane] = __float2bfloat16(e0 * inv);
    ap[lane + 64] = __float2bfloat16(e1 * inv);
  }
}

// ---------------- context: batched 64-tile GEMM (R11) ----------------
__global__ __launch_bounds__(256) void ctx_kernel(
    const __hip_bfloat16* __restrict__ alphab, const __hip_bfloat16* __restrict__ ehsT,
    __hip_bfloat16* __restrict__ catbCtx) {
  __shared__ __align__(16) char AlB[8192], BlB[8192];
  const int z = blockIdx.z;
  gemm64_impl(alphab + (size_t)z * 128 * 128, 128,
              ehsT + (size_t)z * 1024 * 128, 128, nullptr, nullptr, nullptr, 0,
              nullptr, catbCtx + (size_t)z * 128 * 1536, 1536, 128, 0, 0,
              blockIdx.y * 64, blockIdx.x * 64, AlB, BlB);
}

// ---------------- comb (R11) ----------------
__global__ __launch_bounds__(256) void comb_kernel(
    const __hip_bfloat16* __restrict__ catb, const __hip_bfloat16* __restrict__ combw,
    const float* __restrict__ comb_b, __hip_bfloat16* __restrict__ combb) {
  __shared__ __align__(16) char AlB[8192], BlB[8192];
  gemm64_impl(catb, 1536, combw, 1536, comb_b, nullptr, nullptr, 0, nullptr,
              combb, 512, 1536, 1, 0, blockIdx.y * 64, blockIdx.x * 64, AlB, BlB);
}

// ---------------- tail: vocab (128-tile) + wg/base (64-tile) merged (R11) ----------------
__global__ __launch_bounds__(256) void tail_kernel(
    const __hip_bfloat16* __restrict__ combb, const __hip_bfloat16* __restrict__ vocw,
    const float* __restrict__ vocab_b, float* __restrict__ out1,
    const int* __restrict__ cmask,
    const __hip_bfloat16* __restrict__ wgw, const float* __restrict__ Wg_b,
    const float* __restrict__ ptr_b, float* __restrict__ wgout,
    float* __restrict__ baseb) {
  __shared__ __align__(16) char smA[16384], smB[16384];
  const int bid = blockIdx.x;
  if (bid < 1008) {
    const int bx = bid % 63, by = bid / 63;
    gemm128_impl<0, 1, 0>(combb, 512, vocw, 512, vocab_b, out1, V_, nullptr, 0,
                          V_, 512, cmask, V_, by * 128, bx * 128, smA, smB);
  } else {
    const int l = bid - 1008;
    const int bx = l % 10, by = l / 10;
    gemm64_impl(combb, 512, wgw, 512, Wg_b, ptr_b, wgout, 512, baseb, nullptr,
                0, 512, 0, 2, by * 64, bx * 64, smA, smB);
  }
}

// ---------------- pointer head assembly (R11) ----------------
__global__ __launch_bounds__(256) void pointer_kernel(
    const float* __restrict__ base, const float* __restrict__ wgout,
    const float* __restrict__ ptr_W, const float* __restrict__ ps_W,
    const float* __restrict__ ps_b, const int* __restrict__ src_mask,
    float* __restrict__ out0) {
  const int bt = blockIdx.x;
  const int b = bt >> 7, t = bt & 127;
  const int tid = threadIdx.x;
  __shared__ float r0[4], r1[4], r2[4], fin[3];
  float off_p = 0.f, diag_p = 0.f, sent_p;
  if (tid < 128) {
    const float ba = base[(size_t)bt * 128 + tid];
    const float pw = ps_W[tid];
    off_p = tanhf(ba) * pw;
    diag_p = tanhf(ba + ptr_W[tid * 513 + 512]) * pw;
  }
  sent_p = wgout[(size_t)bt * 512 + tid] + wgout[(size_t)bt * 512 + 256 + tid];
  off_p = wave_sum(off_p);
  diag_p = wave_sum(diag_p);
  sent_p = wave_sum(sent_p);
  const int wid = tid >> 6, lane = tid & 63;
  if (lane == 0) { r0[wid] = off_p; r1[wid] = diag_p; r2[wid] = sent_p; }
  __syncthreads();
  if (tid == 0) {
    const float psb = ps_b[0];
    fin[0] = r0[0] + r0[1] + r0[2] + r0[3] + psb;
    fin[1] = r1[0] + r1[1] + r1[2] + r1[3] + psb;
    fin[2] = r2[0] + r2[1] + r2[2] + r2[3];
  }
  __syncthreads();
  const float s_off = fin[0], s_diag = fin[1], sent = fin[2];
  if (tid < 129) {
    float v;
    if (tid == 128) v = sent;
    else {
      v = (tid == t) ? s_diag : s_off;
      if (src_mask[b * 128 + tid] == 0) v = NEGV;
    }
    out0[(size_t)bt * 129 + tid] = v;
  }
}

// ---------------- launch ----------------
extern "C" void kernel_launch(void* const* d_in, const int* in_sizes, int n_in,
                              void* d_out, int out_size, void* d_ws, size_t ws_size,
                              hipStream_t stream) {
  const int* src_ids   = (const int*)d_in[0];
  const int* src_mask  = (const int*)d_in[1];
  const int* cmask     = (const int*)d_in[2];
  const float* emb     = (const float*)d_in[3];
  const float* Wih_f   = (const float*)d_in[4];
  const float* Whh_f   = (const float*)d_in[5];
  const float* b_f     = (const float*)d_in[6];
  const float* Wih_b   = (const float*)d_in[7];
  const float* Whh_b   = (const float*)d_in[8];
  const float* b_b     = (const float*)d_in[9];
  const float* Wih_d   = (const float*)d_in[10];
  const float* Whh_d   = (const float*)d_in[11];
  const float* b_d     = (const float*)d_in[12];
  const float* W1      = (const float*)d_in[13];
  const float* W2      = (const float*)d_in[14];
  const float* v_att   = (const float*)d_in[15];
  const float* comb_W  = (const float*)d_in[16];
  const float* comb_b  = (const float*)d_in[17];
  const float* vocab_W = (const float*)d_in[18];
  const float* vocab_b = (const float*)d_in[19];
  const float* Wg_W    = (const float*)d_in[20];
  const float* Wg_b    = (const float*)d_in[21];
  const float* ptr_W   = (const float*)d_in[22];
  const float* ptr_b   = (const float*)d_in[23];
  const float* ps_W    = (const float*)d_in[24];
  const float* ps_b    = (const float*)d_in[25];
  (void)in_sizes; (void)n_in; (void)out_size; (void)ws_size;

  char* wsb = (char*)d_ws;
  size_t o = 0;
  auto alloc = [&](size_t bytes) { char* p = wsb + o; o = (o + bytes + 255) & ~(size_t)255; return p; };
  __hip_bfloat16* xb      = (__hip_bfloat16*)alloc((size_t)BN_ * E_ * 2);
  __hip_bfloat16* xpT     = (__hip_bfloat16*)alloc((size_t)3 * BN_ * 2048 * 2);
  __hip_bfloat16* ehsb    = (__hip_bfloat16*)alloc((size_t)BN_ * 1024 * 2);
  __hip_bfloat16* ehsT    = (__hip_bfloat16*)alloc((size_t)16 * 1024 * 128 * 2);
  __hip_bfloat16* catb    = (__hip_bfloat16*)alloc((size_t)BN_ * 1536 * 2);
  float* dterm            = (float*)alloc((size_t)BN_ * 512 * 4);
  __hip_bfloat16* etT     = (__hip_bfloat16*)alloc((size_t)16 * 512 * 128 * 2);
  __hip_bfloat16* alphab  = (__hip_bfloat16*)alloc((size_t)BN_ * 128 * 2);
  __hip_bfloat16* combb   = (__hip_bfloat16*)alloc((size_t)BN_ * 512 * 2);
  float* wgout            = (float*)alloc((size_t)BN_ * 512 * 4);
  float* baseb            = (float*)alloc((size_t)BN_ * 128 * 4);
  __hip_bfloat16* hbuf    = (__hip_bfloat16*)alloc((size_t)3 * 128 * 8192 * 2);
  __hip_bfloat16* wih16   = (__hip_bfloat16*)alloc((size_t)3 * 2048 * 384 * 2);
  __hip_bfloat16* w1_16   = (__hip_bfloat16*)alloc((size_t)512 * 512 * 2);
  __hip_bfloat16* w2_16   = (__hip_bfloat16*)alloc((size_t)512 * 1024 * 2);
  __hip_bfloat16* combw16 = (__hip_bfloat16*)alloc((size_t)512 * 1536 * 2);
  __hip_bfloat16* vocw16  = (__hip_bfloat16*)alloc((size_t)8000 * 512 * 2);
  __hip_bfloat16* wgw16   = (__hip_bfloat16*)alloc((size_t)512 * 512 * 2);
  __hip_bfloat16* ptrw16  = (__hip_bfloat16*)alloc((size_t)128 * 512 * 2);

  float* out0 = (float*)d_out;
  float* out1 = out0 + (size_t)BN_ * 129;

  CastArgs c1;
  {
    const float* s3[3] = {Wih_f, Wih_b, Wih_d};
    int acc = 0;
    for (int k = 0; k < 3; ++k) {
      c1.s[k] = s3[k];
      c1.d[k] = (unsigned long long)(wih16 + (size_t)k * 2048 * 384);
      c1.base[k] = acc;
      acc += 2048 * 384;
    }
    for (int k = 3; k < 6; ++k) { c1.s[k] = nullptr; c1.d[k] = 0; c1.base[k] = 0x7fffffff; }
    c1.total = acc; c1.special = -1;
  }
  CastArgs c2;
  {
    const float* s6[6] = {W1, W2, comb_W, vocab_W, Wg_W, ptr_W};
    __hip_bfloat16* d6[6] = {w1_16, w2_16, combw16, vocw16, wgw16, ptrw16};
    int ns[6] = {512 * 512, 512 * 1024, 512 * 1536, 8000 * 512, 512 * 512, 128 * 512};
    int acc = 0;
    for (int k = 0; k < 6; ++k) {
      c2.s[k] = s6[k]; c2.d[k] = (unsigned long long)d6[k]; c2.base[k] = acc;
      acc += ns[k];
    }
    c2.total = acc; c2.special = 5;
  }

  // 1) prologue: embed + hbuf sentinel memset + cast1
  prologue_kernel<<<544, 256, 0, stream>>>(src_ids, emb, xb, hbuf, c1);

  // 2) xproj -> xprojT layout
  xproj_kernel<<<dim3(16, 16, 3), 256, 0, stream>>>(xb, wih16, b_f, b_b, b_d, xpT);

  // 3) fused lstm + cast2
  hipError_t e1 = hipFuncSetAttribute((const void*)fused_kernel,
                      hipFuncAttributeMaxDynamicSharedMemorySize, 147968);
  (void)e1;
  fused_kernel<<<160, 256, 147968, stream>>>(
      xpT, Whh_f, Whh_b, Whh_d, hbuf, ehsb, ehsT, catb, c2);

  // 4) dterm + etT merged
  qk_kernel<<<512, 256, 0, stream>>>(catb, ehsb, w1_16, w2_16, dterm, etT);

  // 5) score + softmax
  score_kernel<<<16 * 32, 256, 0, stream>>>(dterm, etT, v_att, src_mask, alphab);

  // 6) context
  ctx_kernel<<<dim3(16, 2, 16), 256, 0, stream>>>(alphab, ehsT, catb + 512);

  // 7) combined
  comb_kernel<<<dim3(8, 32), 256, 0, stream>>>(catb, combw16, comb_b, combb);

  // 8) vocab (+cmask) and wg/base merged
  tail_kernel<<<1328, 256, 0, stream>>>(combb, vocw16, vocab_b, out1, cmask,
                                        wgw16, Wg_b, ptr_b, wgout, baseb);

  // 9) pointer head
  pointer_kernel<<<BN_, 256, 0, stream>>>(baseb, wgout, ptr_W, ps_W, ps_b, src_mask, out0);
}

// Round 16
// 582.514 us; speedup vs baseline: 1.5502x; 1.0548x over previous
//
#include <hip/hip_runtime.h>
#include <hip/hip_bf16.h>
#include <math.h>

#define NEGV -1000000000.0f

static constexpr int B_ = 16, N_ = 128, BN_ = 2048;
static constexpr int E_ = 384, V_ = 8000;

typedef __attribute__((ext_vector_type(8))) short short8v;
typedef __attribute__((ext_vector_type(4))) float f32x4;

// ---------------- helpers ----------------
__device__ inline float wave_sum(float v) {
#pragma unroll
  for (int o = 32; o; o >>= 1) v += __shfl_xor(v, o);
  return v;
}
__device__ inline float wave_max(float v) {
#pragma unroll
  for (int o = 32; o; o >>= 1) v = fmaxf(v, __shfl_xor(v, o));
  return v;
}
__device__ inline float fast_tanh(float x) {
  return 1.f - 2.f / (1.f + __expf(2.f * x));
}
__device__ inline float fast_tanh_pre(float x2) {
  return 1.f - 2.f / (1.f + __expf(x2));
}
__device__ inline float fast_sig(float x) {
  return 1.f / (1.f + __expf(-x));
}
__device__ __forceinline__ void gl16(const void* g, void* l) {
  __builtin_amdgcn_global_load_lds((const __attribute__((address_space(1))) void*)g,
                                   (__attribute__((address_space(3))) void*)l, 16, 0, 0);
}

// ---------------- multi-segment fp32 -> bf16 cast ----------------
struct CastArgs {
  const float* s[6];
  unsigned long long d[6];
  int base[6];
  int total;
  int special;
};
__device__ inline void cast_body(const CastArgs& a, int gsize, int gid0) {
  const int nq = a.total >> 2;
  for (int q = gid0; q < nq; q += gsize) {
    const int e = q << 2;
    int k = 5;
    while (e < a.base[k]) --k;
    const int i = e - a.base[k];
    __hip_bfloat16* dst = (__hip_bfloat16*)a.d[k] + i;
    if (k == a.special) {
      const int row = i >> 9, col = i & 511;
      const float* sp = a.s[k] + (size_t)row * 513 + col;
#pragma unroll
      for (int u = 0; u < 4; ++u) dst[u] = __float2bfloat16(sp[u]);
    } else {
      float4 v = *(const float4*)(a.s[k] + i);
      __hip_bfloat16 h0 = __float2bfloat16(v.x), h1 = __float2bfloat16(v.y);
      __hip_bfloat16 h2 = __float2bfloat16(v.z), h3 = __float2bfloat16(v.w);
      ushort4 u4 = {*(unsigned short*)&h0, *(unsigned short*)&h1,
                    *(unsigned short*)&h2, *(unsigned short*)&h3};
      *(ushort4*)dst = u4;
    }
  }
}

// ---------------- prologue: embed + hbuf sentinel-memset + cast1 ----------------
__global__ __launch_bounds__(256) void prologue_kernel(
    const int* __restrict__ ids, const float* __restrict__ emb,
    __hip_bfloat16* __restrict__ xb, __hip_bfloat16* __restrict__ hbuf,
    CastArgs c1) {
  const int bid = blockIdx.x, tid = threadIdx.x;
  if (bid < 256) {
    for (int row = bid; row < 2048; row += 256) {
      const int id = ids[row];
      for (int e = tid; e < E_; e += 256)
        xb[(size_t)row * E_ + e] = __float2bfloat16(emb[(size_t)id * E_ + e]);
    }
  } else if (bid < 288) {
    const unsigned total = 3u * 128u * 8192u * 2u;
    const float pf = __builtin_bit_cast(float, 0x7f7f7f7fu);
    f32x4 pat = {pf, pf, pf, pf};
    char* base = (char*)hbuf;
    for (unsigned off = (unsigned)((bid - 256) * 256 + tid) * 16u; off < total;
         off += 32u * 256u * 16u) {
      asm volatile("global_store_dwordx4 %0, %1, %2 sc0 sc1"
                   :: "v"(off), "v"(pat), "s"(base) : "memory");
    }
  } else {
    cast_body(c1, 256 * 256, (bid - 288) * 256 + tid);
  }
}

// ---------------- 128x128-tile bf16 MFMA GEMM body ----------------
// MASK: 0 none, 1 int cmask.
template <int ACT, int MASK>
__device__ __forceinline__ void gemm128_impl(
    const __hip_bfloat16* A, int lda, const __hip_bfloat16* W, int ldw,
    const float* bias, float* C, int ldc, __hip_bfloat16* Cb, int ldcb,
    int N, int K, const int* maskp, int ldm, int m0, int n0,
    char* smA, char* smB) {
  const int tid = threadIdx.x;
  const int wid = tid >> 6, lane = tid & 63;
  const int nkt = K >> 5;
  const int rm = (wid >> 1) << 6, rn = (wid & 1) << 6;
  const int lrow = lane & 15, kq = lane >> 4;
  const int fs = ((lrow >> 1) & 3) << 4;

  f32x4 acc[4][4];
#pragma unroll
  for (int i = 0; i < 4; ++i)
#pragma unroll
    for (int j = 0; j < 4; ++j) acc[i][j] = {0.f, 0.f, 0.f, 0.f};

  auto stage = [&](int bi, int kt) {
#pragma unroll
    for (int c = 0; c < 2; ++c) {
      const int p = ((c * 4 + wid) << 6) + lane;
      const int row = p >> 2, cb = (p & 3) << 4;
      const int sw = ((row >> 1) & 3) << 4;
      const unsigned loff = (unsigned)__builtin_amdgcn_readfirstlane((c * 4 + wid) << 10);
      {
        const char* src = (const char*)A + ((size_t)(m0 + row) * lda + (size_t)kt * 32) * 2 + (cb ^ sw);
        gl16(src, smA + bi * 8192 + loff);
      }
      {
        int gr = n0 + row;
        if (gr >= N) gr = N - 1;
        const char* src = (const char*)W + ((size_t)gr * ldw + (size_t)kt * 32) * 2 + (cb ^ sw);
        gl16(src, smB + bi * 8192 + loff);
      }
    }
  };
  auto compute = [&](int bi) {
    const char* Ab = smA + bi * 8192;
    const char* Bb = smB + bi * 8192;
    const int roff = (kq << 4) ^ fs;
    short8v a[4], b[4];
#pragma unroll
    for (int i = 0; i < 4; ++i)
      a[i] = *(const short8v*)(Ab + (rm + i * 16 + lrow) * 64 + roff);
#pragma unroll
    for (int j = 0; j < 4; ++j)
      b[j] = *(const short8v*)(Bb + (rn + j * 16 + lrow) * 64 + roff);
#pragma unroll
    for (int i = 0; i < 4; ++i)
#pragma unroll
      for (int j = 0; j < 4; ++j)
        acc[i][j] = __builtin_amdgcn_mfma_f32_16x16x32_bf16(a[i], b[j], acc[i][j], 0, 0, 0);
  };

  stage(0, 0);
  for (int kt = 0; kt < nkt; ++kt) {
    __syncthreads();
    if (kt + 1 < nkt) stage((kt + 1) & 1, kt + 1);
    compute(kt & 1);
  }

#pragma unroll
  for (int i = 0; i < 4; ++i) {
#pragma unroll
    for (int r = 0; r < 4; ++r) {
      const int m = m0 + rm + i * 16 + kq * 4 + r;
#pragma unroll
      for (int j = 0; j < 4; ++j) {
        const int n = n0 + rn + j * 16 + lrow;
        if (n < N) {
          float v = acc[i][j][r] + (bias ? bias[n] : 0.f);
          if (ACT == 1) v = fast_tanh(v);
          if (MASK == 1) {
            if (maskp[(size_t)m * ldm + n] == 0) v = NEGV;
          }
          if (C) C[(size_t)m * ldc + n] = v;
          if (Cb) Cb[(size_t)m * ldcb + n] = __float2bfloat16(v);
        }
      }
    }
  }
}

// ---------------- 64x64-tile bf16 MFMA GEMM body ----------------
__device__ __forceinline__ void gemm64_impl(
    const __hip_bfloat16* A, int lda, const __hip_bfloat16* W, int ldw,
    const float* bias, const float* bias2,
    float* C, int ldc, float* C2, __hip_bfloat16* Cb, int ldcb,
    int K, int act, int trout, int m0, int n0, char* AlB, char* BlB) {
  const int tid = threadIdx.x;
  const int wid = tid >> 6, lane = tid & 63;
  const int nkt = K >> 5;
  const int rm = (wid >> 1) << 5, rn = (wid & 1) << 5;
  const int lrow = lane & 15, kq = lane >> 4;
  const int fs = ((lrow >> 1) & 3) << 4;

  f32x4 acc[2][2];
#pragma unroll
  for (int i = 0; i < 2; ++i)
#pragma unroll
    for (int j = 0; j < 2; ++j) acc[i][j] = {0.f, 0.f, 0.f, 0.f};

  auto stage = [&](int bi, int kt) {
    const int row = tid >> 2, cb = (tid & 3) << 4;
    const int sw = ((row >> 1) & 3) << 4;
    const unsigned loff = (unsigned)__builtin_amdgcn_readfirstlane(wid << 10);
    {
      const char* src = (const char*)A + ((size_t)(m0 + row) * lda + (size_t)kt * 32) * 2 + (cb ^ sw);
      gl16(src, AlB + bi * 4096 + loff);
    }
    {
      const char* src = (const char*)W + ((size_t)(n0 + row) * ldw + (size_t)kt * 32) * 2 + (cb ^ sw);
      gl16(src, BlB + bi * 4096 + loff);
    }
  };
  auto compute = [&](int bi) {
    const char* Ab = AlB + bi * 4096;
    const char* Bb = BlB + bi * 4096;
    const int roff = (kq << 4) ^ fs;
    short8v a[2], b[2];
#pragma unroll
    for (int i = 0; i < 2; ++i)
      a[i] = *(const short8v*)(Ab + (rm + i * 16 + lrow) * 64 + roff);
#pragma unroll
    for (int j = 0; j < 2; ++j)
      b[j] = *(const short8v*)(Bb + (rn + j * 16 + lrow) * 64 + roff);
#pragma unroll
    for (int i = 0; i < 2; ++i)
#pragma unroll
      for (int j = 0; j < 2; ++j)
        acc[i][j] = __builtin_amdgcn_mfma_f32_16x16x32_bf16(a[i], b[j], acc[i][j], 0, 0, 0);
  };

  stage(0, 0);
  for (int kt = 0; kt < nkt; ++kt) {
    __syncthreads();
    if (kt + 1 < nkt) stage((kt + 1) & 1, kt + 1);
    compute(kt & 1);
  }

#pragma unroll
  for (int i = 0; i < 2; ++i) {
#pragma unroll
    for (int r = 0; r < 4; ++r) {
      const int m = m0 + rm + i * 16 + kq * 4 + r;
#pragma unroll
      for (int j = 0; j < 2; ++j) {
        const int n = n0 + rn + j * 16 + lrow;
        float v = acc[i][j][r];
        if (trout == 2) {
          if (n < 512) {
            C[(size_t)m * ldc + n] = fast_tanh(v + bias[n]);
          } else {
            C2[(size_t)m * 128 + (n - 512)] = v + bias2[n - 512];
          }
        } else {
          if (act == 2) v *= 2.f;
          else {
            v += (bias ? bias[n] : 0.f);
            if (act == 1) v = fast_tanh(v);
          }
          if (trout == 1) {
            Cb[(((size_t)(m >> 7) * 512 + n) << 7) + (m & 127)] = __float2bfloat16(v);
          } else {
            if (C) C[(size_t)m * ldc + n] = v;
            if (Cb) Cb[(size_t)m * ldcb + n] = __float2bfloat16(v);
          }
        }
      }
    }
  }
}

// ---------------- xproj: z-batched 128-tile GEMM (normal row-major out) ----------------
__global__ __launch_bounds__(256) void xproj_kernel(
    const __hip_bfloat16* __restrict__ A, const __hip_bfloat16* __restrict__ Wih,
    const float* __restrict__ b0, const float* __restrict__ b1,
    const float* __restrict__ b2, __hip_bfloat16* __restrict__ xproj16) {
  __shared__ __align__(16) char smA[16384], smB[16384];
  const int z = blockIdx.z;
  const float* bias = (z == 0) ? b0 : (z == 1 ? b1 : b2);
  gemm128_impl<0, 0>(A, E_, Wih + (size_t)z * 2048 * 384, E_, bias,
                     nullptr, 0, xproj16 + (size_t)z * BN_ * 2048, 2048,
                     2048, E_, nullptr, 0, blockIdx.y * 128,
                     blockIdx.x * 128, smA, smB);
}

// ---------------- FUSED: lstm (96 blocks) + cast2 (64 blocks) ----------------
__global__ __launch_bounds__(256) void fused_kernel(
    const __hip_bfloat16* __restrict__ xp16,   // [3][2048][2048] row-major
    const float* __restrict__ whhF, const float* __restrict__ whhB,
    const float* __restrict__ whhD,
    __hip_bfloat16* __restrict__ hbuf,
    __hip_bfloat16* __restrict__ ehsb, __hip_bfloat16* __restrict__ ehsT,
    __hip_bfloat16* __restrict__ catb,
    CastArgs ca2) {
  extern __shared__ char sm[];
  const int bid = blockIdx.x;
  const int tid = threadIdx.x;

  if (bid >= 96) {  // ---- cast2 role ----
    cast_body(ca2, 64 * 256, (bid - 96) * 256 + tid);
    return;
  }

  // ---- LSTM role ----
  const int l = bid >> 5, g = bid & 31;
  const int lane = tid & 63, wid = tid >> 6;
  char* smW = sm;                                   // 65536
  char* smH = sm + 65536;                           // 16384
  __hip_bfloat16* hout = (__hip_bfloat16*)(sm + 65536 + 16384);  // 512
  char* hist = sm + 65536 + 16384 + 512;            // 65536

  const float* wsrc = (l == 0) ? whhF : ((l == 1) ? whhB : whhD);
  auto cv = [](float x) -> unsigned {
    __hip_bfloat16 h = __float2bfloat16(x);
    return (unsigned)*(unsigned short*)&h;
  };
  for (int p = tid; p < 4096; p += 256) {
    const int r = p >> 6, cb = (p & 63) << 4;
    const int grow = (r & 3) * 512 + (g << 4) + (r >> 2);
    const float* srcp = wsrc + (size_t)grow * 512 + ((p & 63) << 3);
    float4 u0 = *(const float4*)srcp;
    float4 u1 = *(const float4*)(srcp + 4);
    uint4 q;
    q.x = cv(u0.x) | (cv(u0.y) << 16);
    q.y = cv(u0.z) | (cv(u0.w) << 16);
    q.z = cv(u1.x) | (cv(u1.y) << 16);
    q.w = cv(u1.z) | (cv(u1.w) << 16);
    *(uint4*)(smW + r * 1024 + (cb ^ ((r & 7) << 4))) = q;
  }

  const int lrow = lane & 15, kq = lane >> 4;
  const int swz = (lrow & 7) << 4;
  const char* aB = smW + (wid * 16 + lrow) * 1024;
  const char* bB = smH + lrow * 1024;
  const int dl16 = wid * 4 + kq;
  const int dg = (g << 4) + dl16;
  const int bb = lrow;
  const bool rev = (l == 1);
  const __hip_bfloat16* xl = xp16 + (size_t)l * 2048 * 2048;
  __hip_bfloat16* hb_l = hbuf + (size_t)l * 128 * 8192;
  const int gq = tid >> 3;
  const int b0 = (tid & 7) * 2;
  const int gb = gq * 32;
  const int sw0 = (b0 & 7) << 4, sw1 = ((b0 + 1) & 7) << 4;
  float c = 0.f;

  for (int s = 0; s < 128; ++s) {
    const int t = rev ? 127 - s : s;
    const size_t xro = (size_t)(bb * 128 + t) * 2048 + dg;
    const float xgi = __bfloat162float(xl[xro]);
    const float xgf = __bfloat162float(xl[xro + 512]);
    const float xgg = __bfloat162float(xl[xro + 1024]);
    const float xgo = __bfloat162float(xl[xro + 1536]);

    if (s > 0) {
      if (gq != g) {
        const char* hsrc = (const char*)(hb_l + (size_t)(s - 1) * 8192);
        const unsigned loff = (unsigned)(tid * 64);
        unsigned hv;
        while (true) {
          asm volatile(
              "global_load_ushort %0, %1, %2 sc0 sc1\n\t"
              "s_waitcnt vmcnt(0)"
              : "=&v"(hv) : "v"(loff), "s"(hsrc) : "memory");
          if ((hv & 0xffffu) != 0x7f7fu) break;
          __builtin_amdgcn_s_sleep(1);
        }
        f32x4 q0, q1, q2, q3;
        asm volatile(
            "global_load_dwordx4 %0, %4, %5 sc0 sc1\n\t"
            "global_load_dwordx4 %1, %4, %5 offset:16 sc0 sc1\n\t"
            "global_load_dwordx4 %2, %4, %5 offset:32 sc0 sc1\n\t"
            "global_load_dwordx4 %3, %4, %5 offset:48 sc0 sc1\n\t"
            "s_waitcnt vmcnt(0)"
            : "=&v"(q0), "=&v"(q1), "=&v"(q2), "=&v"(q3)
            : "v"(loff), "s"(hsrc) : "memory");
        *(f32x4*)(smH + b0 * 1024 + (gb ^ sw0)) = q0;
        *(f32x4*)(smH + b0 * 1024 + ((gb + 16) ^ sw0)) = q1;
        *(f32x4*)(smH + (b0 + 1) * 1024 + (gb ^ sw1)) = q2;
        *(f32x4*)(smH + (b0 + 1) * 1024 + ((gb + 16) ^ sw1)) = q3;
      } else {
        const char* hl = (const char*)hout + b0 * 32;
        f32x4 c0 = *(const f32x4*)(hl);
        f32x4 c1 = *(const f32x4*)(hl + 16);
        f32x4 c2 = *(const f32x4*)(hl + 32);
        f32x4 c3 = *(const f32x4*)(hl + 48);
        *(f32x4*)(smH + b0 * 1024 + (gb ^ sw0)) = c0;
        *(f32x4*)(smH + b0 * 1024 + ((gb + 16) ^ sw0)) = c1;
        *(f32x4*)(smH + (b0 + 1) * 1024 + (gb ^ sw1)) = c2;
        *(f32x4*)(smH + (b0 + 1) * 1024 + ((gb + 16) ^ sw1)) = c3;
      }
    } else {
      const f32x4 z = {0.f, 0.f, 0.f, 0.f};
      *(f32x4*)(smH + b0 * 1024 + (gb ^ sw0)) = z;
      *(f32x4*)(smH + b0 * 1024 + ((gb + 16) ^ sw0)) = z;
      *(f32x4*)(smH + (b0 + 1) * 1024 + (gb ^ sw1)) = z;
      *(f32x4*)(smH + (b0 + 1) * 1024 + ((gb + 16) ^ sw1)) = z;
    }
    __syncthreads();  // A

    f32x4 acc0 = {0.f, 0.f, 0.f, 0.f}, acc1 = {0.f, 0.f, 0.f, 0.f};
#pragma unroll
    for (int kt = 0; kt < 16; kt += 2) {
      const int off0 = ((kt * 64 + (kq << 4)) ^ swz);
      const int off1 = (((kt + 1) * 64 + (kq << 4)) ^ swz);
      short8v a0 = *(const short8v*)(aB + off0);
      short8v b0v = *(const short8v*)(bB + off0);
      short8v a1 = *(const short8v*)(aB + off1);
      short8v b1v = *(const short8v*)(bB + off1);
      acc0 = __builtin_amdgcn_mfma_f32_16x16x32_bf16(a0, b0v, acc0, 0, 0, 0);
      acc1 = __builtin_amdgcn_mfma_f32_16x16x32_bf16(a1, b1v, acc1, 0, 0, 0);
    }
    const f32x4 acc = acc0 + acc1;

    const float gi = acc[0] + xgi;
    const float gf = acc[1] + xgf;
    const float gg = acc[2] + xgg;
    const float go = acc[3] + xgo;
    c = fmaf(fast_sig(gf), c, fast_sig(gi) * fast_tanh(gg));
    const float h = fast_sig(go) * fast_tanh(c);
    __hip_bfloat16 hb16 = __float2bfloat16(h);
    const unsigned short hraw = *(unsigned short*)&hb16;
    hout[bb * 16 + dl16] = hb16;
    *(unsigned short*)(hist + s * 512 + (bb * 16 + dl16) * 2) = hraw;
    __syncthreads();  // B

    if (s < 127 && wid == (s & 3) && (lane < 32)) {
      f32x4 hv4 = *(const f32x4*)((const char*)hout + lane * 16);
      char* hdst = (char*)(hb_l + (size_t)s * 8192);
      asm volatile("global_store_dwordx4 %0, %1, %2 sc0 sc1"
                   :: "v"((unsigned)((g << 9) + lane * 16)), "v"(hv4), "s"(hdst)
                   : "memory");
    }
  }

  // ---- epilogue: write own slice of ehsb/ehsT/catb from LDS history ----
  __syncthreads();
  const int bb2 = tid >> 4, lo2 = tid & 15;
  if (l < 2) {
    const int hoff = (bb2 * 16 + lo2) * 2;
    char* dstT = (char*)(ehsT + ((size_t)bb2 * 1024 + l * 512 + (g << 4) + lo2) * 128);
    for (int tc = 0; tc < 128; tc += 32) {
      unsigned v[16];
#pragma unroll
      for (int w = 0; w < 16; ++w) {
        const int t0 = tc + 2 * w;
        const int s0 = rev ? 127 - t0 : t0;
        const int s1 = rev ? 126 - t0 : t0 + 1;
        unsigned a = *(const unsigned short*)(hist + s0 * 512 + hoff);
        unsigned b2 = *(const unsigned short*)(hist + s1 * 512 + hoff);
        v[w] = a | (b2 << 16);
      }
#pragma unroll
      for (int q = 0; q < 4; ++q)
        *(uint4*)(dstT + tc * 2 + q * 16) =
            make_uint4(v[q * 4], v[q * 4 + 1], v[q * 4 + 2], v[q * 4 + 3]);
    }
    for (int k = 0; k < 8; ++k) {
      const int t = lo2 * 8 + k;
      const int s0 = rev ? 127 - t : t;
      const char* srcp = hist + s0 * 512 + bb2 * 32;
      uint4 ra = *(const uint4*)srcp;
      uint4 rb = *(const uint4*)(srcp + 16);
      char* dp = (char*)(ehsb + ((size_t)(bb2 * 128 + t)) * 1024 + l * 512 + (g << 4));
      *(uint4*)dp = ra;
      *(uint4*)(dp + 16) = rb;
    }
  } else {
    for (int k = 0; k < 8; ++k) {
      const int t = lo2 * 8 + k;
      const char* srcp = hist + t * 512 + bb2 * 32;
      uint4 ra = *(const uint4*)srcp;
      uint4 rb = *(const uint4*)(srcp + 16);
      char* dp = (char*)(catb + ((size_t)(bb2 * 128 + t)) * 1536 + (g << 4));
      *(uint4*)dp = ra;
      *(uint4*)(dp + 16) = rb;
    }
  }
}

// ---------------- qk: dterm + etT merged ----------------
__global__ __launch_bounds__(256) void qk_kernel(
    const __hip_bfloat16* __restrict__ catb, const __hip_bfloat16* __restrict__ ehsb,
    const __hip_bfloat16* __restrict__ w1, const __hip_bfloat16* __restrict__ w2,
    float* __restrict__ dterm, __hip_bfloat16* __restrict__ etT) {
  __shared__ __align__(16) char AlB[8192], BlB[8192];
  const int bid = blockIdx.x;
  if (bid < 256) {
    const int bx = bid & 7, by = bid >> 3;
    gemm64_impl(catb, 1536, w1, 512, nullptr, nullptr, dterm, 512, nullptr,
                nullptr, 0, 512, 2, 0, by * 64, bx * 64, AlB, BlB);
  } else {
    const int l = bid - 256;
    const int bx = l & 7, by = l >> 3;
    gemm64_impl(ehsb, 1024, w2, 1024, nullptr, nullptr, nullptr, 0, nullptr,
                etT, 0, 1024, 2, 1, by * 64, bx * 64, AlB, BlB);
  }
}

// ---------------- score + softmax -> alpha; 4 t's per block ----------------
__global__ __launch_bounds__(256) void score_kernel(
    const float* __restrict__ dterm, const __hip_bfloat16* __restrict__ etT,
    const float* __restrict__ v_att, const int* __restrict__ src_mask,
    __hip_bfloat16* __restrict__ alphab) {
  const int b = blockIdx.x >> 5, tg = blockIdx.x & 31;
  const int t0 = tg * 4;
  const int tid = threadIdx.x;
  __shared__ float dt[4][512], vs[512], red[4][4][128], al[4][128];
  for (int i = tid; i < 2048; i += 256)
    dt[i >> 9][i & 511] = dterm[((size_t)(b * 128 + t0 + (i >> 9))) * 512 + (i & 511)];
  vs[tid] = v_att[tid];
  vs[tid + 256] = v_att[256 + tid];
  __syncthreads();
  const int n0 = (tid & 63) << 1, ah = tid >> 6;
  {
    const __hip_bfloat16* ep = etT + (((size_t)b * 512 + ah * 128) << 7) + n0;
    const float* vp = vs + ah * 128;
    const float* dp0 = &dt[0][ah * 128];
    const float* dp1 = &dt[1][ah * 128];
    const float* dp2 = &dt[2][ah * 128];
    const float* dp3 = &dt[3][ah * 128];
    float p00 = 0, p01 = 0, p10 = 0, p11 = 0, p20 = 0, p21 = 0, p30 = 0, p31 = 0;
    for (int q = 0; q < 128; ++q) {
      const unsigned u = *(const unsigned*)(ep + ((size_t)q << 7));
      unsigned u0 = u << 16, u1 = u & 0xffff0000u;
      const float e0 = __builtin_bit_cast(float, u0);
      const float e1 = __builtin_bit_cast(float, u1);
      const float va = vp[q];
      p00 = fmaf(va, fast_tanh_pre(dp0[q] + e0), p00);
      p01 = fmaf(va, fast_tanh_pre(dp0[q] + e1), p01);
      p10 = fmaf(va, fast_tanh_pre(dp1[q] + e0), p10);
      p11 = fmaf(va, fast_tanh_pre(dp1[q] + e1), p11);
      p20 = fmaf(va, fast_tanh_pre(dp2[q] + e0), p20);
      p21 = fmaf(va, fast_tanh_pre(dp2[q] + e1), p21);
      p30 = fmaf(va, fast_tanh_pre(dp3[q] + e0), p30);
      p31 = fmaf(va, fast_tanh_pre(dp3[q] + e1), p31);
    }
    red[0][ah][n0] = p00; red[0][ah][n0 + 1] = p01;
    red[1][ah][n0] = p10; red[1][ah][n0 + 1] = p11;
    red[2][ah][n0] = p20; red[2][ah][n0 + 1] = p21;
    red[3][ah][n0] = p30; red[3][ah][n0 + 1] = p31;
  }
  __syncthreads();
#pragma unroll
  for (int tp = 0; tp < 2; ++tp) {
    const int tt = tp * 2 + (tid >> 7);
    const int n = tid & 127;
    float sc = red[tt][0][n] + red[tt][1][n] + red[tt][2][n] + red[tt][3][n];
    if (src_mask[b * 128 + n] == 0) sc = NEGV;
    al[tt][n] = sc;
  }
  __syncthreads();
  {
    const int tt = tid >> 6, lane = tid & 63;
    const float v0 = al[tt][lane], v1 = al[tt][lane + 64];
    const float m = wave_max(fmaxf(v0, v1));
    const float e0 = __expf(v0 - m), e1 = __expf(v1 - m);
    const float inv = 1.f / wave_sum(e0 + e1);
    __hip_bfloat16* ap = alphab + ((size_t)(b * 128 + t0 + tt)) * 128;
    ap[lane] = __float2bfloat16(e0 * inv);
    ap[lane + 64] = __float2bfloat16(e1 * inv);
  }
}

// ---------------- context: batched 64-tile GEMM ----------------
__global__ __launch_bounds__(256) void ctx_kernel(
    const __hip_bfloat16* __restrict__ alphab, const __hip_bfloat16* __restrict__ ehsT,
    __hip_bfloat16* __restrict__ catbCtx) {
  __shared__ __align__(16) char AlB[8192], BlB[8192];
  const int z = blockIdx.z;
  gemm64_impl(alphab + (size_t)z * 128 * 128, 128,
              ehsT + (size_t)z * 1024 * 128, 128, nullptr, nullptr, nullptr, 0,
              nullptr, catbCtx + (size_t)z * 128 * 1536, 1536, 128, 0, 0,
              blockIdx.y * 64, blockIdx.x * 64, AlB, BlB);
}

// ---------------- comb ----------------
__global__ __launch_bounds__(256) void comb_kernel(
    const __hip_bfloat16* __restrict__ catb, const __hip_bfloat16* __restrict__ combw,
    const float* __restrict__ comb_b, __hip_bfloat16* __restrict__ combb) {
  __shared__ __align__(16) char AlB[8192], BlB[8192];
  gemm64_impl(catb, 1536, combw, 1536, comb_b, nullptr, nullptr, 0, nullptr,
              combb, 512, 1536, 1, 0, blockIdx.y * 64, blockIdx.x * 64, AlB, BlB);
}

// ---------------- tail: vocab (128-tile) + wg/base (64-tile) merged ----------------
__global__ __launch_bounds__(256) void tail_kernel(
    const __hip_bfloat16* __restrict__ combb, const __hip_bfloat16* __restrict__ vocw,
    const float* __restrict__ vocab_b, float* __restrict__ out1,
    const int* __restrict__ cmask,
    const __hip_bfloat16* __restrict__ wgw, const float* __restrict__ Wg_b,
    const float* __restrict__ ptr_b, float* __restrict__ wgout,
    float* __restrict__ baseb) {
  __shared__ __align__(16) char smA[16384], smB[16384];
  const int bid = blockIdx.x;
  if (bid < 1008) {
    const int bx = bid % 63, by = bid / 63;
    gemm128_impl<0, 1>(combb, 512, vocw, 512, vocab_b, out1, V_, nullptr, 0,
                       V_, 512, cmask, V_, by * 128, bx * 128, smA, smB);
  } else {
    const int l = bid - 1008;
    const int bx = l % 10, by = l / 10;
    gemm64_impl(combb, 512, wgw, 512, Wg_b, ptr_b, wgout, 512, baseb, nullptr,
                0, 512, 0, 2, by * 64, bx * 64, smA, smB);
  }
}

// ---------------- pointer head assembly ----------------
__global__ __launch_bounds__(256) void pointer_kernel(
    const float* __restrict__ base, const float* __restrict__ wgout,
    const float* __restrict__ ptr_W, const float* __restrict__ ps_W,
    const float* __restrict__ ps_b, const int* __restrict__ src_mask,
    float* __restrict__ out0) {
  const int bt = blockIdx.x;
  const int b = bt >> 7, t = bt & 127;
  const int tid = threadIdx.x;
  __shared__ float r0[4], r1[4], r2[4], fin[3];
  float off_p = 0.f, diag_p = 0.f, sent_p;
  if (tid < 128) {
    const float ba = base[(size_t)bt * 128 + tid];
    const float pw = ps_W[tid];
    off_p = tanhf(ba) * pw;
    diag_p = tanhf(ba + ptr_W[tid * 513 + 512]) * pw;
  }
  sent_p = wgout[(size_t)bt * 512 + tid] + wgout[(size_t)bt * 512 + 256 + tid];
  off_p = wave_sum(off_p);
  diag_p = wave_sum(diag_p);
  sent_p = wave_sum(sent_p);
  const int wid = tid >> 6, lane = tid & 63;
  if (lane == 0) { r0[wid] = off_p; r1[wid] = diag_p; r2[wid] = sent_p; }
  __syncthreads();
  if (tid == 0) {
    const float psb = ps_b[0];
    fin[0] = r0[0] + r0[1] + r0[2] + r0[3] + psb;
    fin[1] = r1[0] + r1[1] + r1[2] + r1[3] + psb;
    fin[2] = r2[0] + r2[1] + r2[2] + r2[3];
  }
  __syncthreads();
  const float s_off = fin[0], s_diag = fin[1], sent = fin[2];
  if (tid < 129) {
    float v;
    if (tid == 128) v = sent;
    else {
      v = (tid == t) ? s_diag : s_off;
      if (src_mask[b * 128 + tid] == 0) v = NEGV;
    }
    out0[(size_t)bt * 129 + tid] = v;
  }
}

// ---------------- launch ----------------
extern "C" void kernel_launch(void* const* d_in, const int* in_sizes, int n_in,
                              void* d_out, int out_size, void* d_ws, size_t ws_size,
                              hipStream_t stream) {
  const int* src_ids   = (const int*)d_in[0];
  const int* src_mask  = (const int*)d_in[1];
  const int* cmask     = (const int*)d_in[2];
  const float* emb     = (const float*)d_in[3];
  const float* Wih_f   = (const float*)d_in[4];
  const float* Whh_f   = (const float*)d_in[5];
  const float* b_f     = (const float*)d_in[6];
  const float* Wih_b   = (const float*)d_in[7];
  const float* Whh_b   = (const float*)d_in[8];
  const float* b_b     = (const float*)d_in[9];
  const float* Wih_d   = (const float*)d_in[10];
  const float* Whh_d   = (const float*)d_in[11];
  const float* b_d     = (const float*)d_in[12];
  const float* W1      = (const float*)d_in[13];
  const float* W2      = (const float*)d_in[14];
  const float* v_att   = (const float*)d_in[15];
  const float* comb_W  = (const float*)d_in[16];
  const float* comb_b  = (const float*)d_in[17];
  const float* vocab_W = (const float*)d_in[18];
  const float* vocab_b = (const float*)d_in[19];
  const float* Wg_W    = (const float*)d_in[20];
  const float* Wg_b    = (const float*)d_in[21];
  const float* ptr_W   = (const float*)d_in[22];
  const float* ptr_b   = (const float*)d_in[23];
  const float* ps_W    = (const float*)d_in[24];
  const float* ps_b    = (const float*)d_in[25];
  (void)in_sizes; (void)n_in; (void)out_size; (void)ws_size;

  char* wsb = (char*)d_ws;
  size_t o = 0;
  auto alloc = [&](size_t bytes) { char* p = wsb + o; o = (o + bytes + 255) & ~(size_t)255; return p; };
  __hip_bfloat16* xb      = (__hip_bfloat16*)alloc((size_t)BN_ * E_ * 2);
  __hip_bfloat16* xproj16 = (__hip_bfloat16*)alloc((size_t)3 * BN_ * 2048 * 2);
  __hip_bfloat16* ehsb    = (__hip_bfloat16*)alloc((size_t)BN_ * 1024 * 2);
  __hip_bfloat16* ehsT    = (__hip_bfloat16*)alloc((size_t)16 * 1024 * 128 * 2);
  __hip_bfloat16* catb    = (__hip_bfloat16*)alloc((size_t)BN_ * 1536 * 2);
  float* dterm            = (float*)alloc((size_t)BN_ * 512 * 4);
  __hip_bfloat16* etT     = (__hip_bfloat16*)alloc((size_t)16 * 512 * 128 * 2);
  __hip_bfloat16* alphab  = (__hip_bfloat16*)alloc((size_t)BN_ * 128 * 2);
  __hip_bfloat16* combb   = (__hip_bfloat16*)alloc((size_t)BN_ * 512 * 2);
  float* wgout            = (float*)alloc((size_t)BN_ * 512 * 4);
  float* baseb            = (float*)alloc((size_t)BN_ * 128 * 4);
  __hip_bfloat16* hbuf    = (__hip_bfloat16*)alloc((size_t)3 * 128 * 8192 * 2);
  __hip_bfloat16* wih16   = (__hip_bfloat16*)alloc((size_t)3 * 2048 * 384 * 2);
  __hip_bfloat16* w1_16   = (__hip_bfloat16*)alloc((size_t)512 * 512 * 2);
  __hip_bfloat16* w2_16   = (__hip_bfloat16*)alloc((size_t)512 * 1024 * 2);
  __hip_bfloat16* combw16 = (__hip_bfloat16*)alloc((size_t)512 * 1536 * 2);
  __hip_bfloat16* vocw16  = (__hip_bfloat16*)alloc((size_t)8000 * 512 * 2);
  __hip_bfloat16* wgw16   = (__hip_bfloat16*)alloc((size_t)512 * 512 * 2);
  __hip_bfloat16* ptrw16  = (__hip_bfloat16*)alloc((size_t)128 * 512 * 2);

  float* out0 = (float*)d_out;
  float* out1 = out0 + (size_t)BN_ * 129;

  CastArgs c1;
  {
    const float* s3[3] = {Wih_f, Wih_b, Wih_d};
    int acc = 0;
    for (int k = 0; k < 3; ++k) {
      c1.s[k] = s3[k];
      c1.d[k] = (unsigned long long)(wih16 + (size_t)k * 2048 * 384);
      c1.base[k] = acc;
      acc += 2048 * 384;
    }
    for (int k = 3; k < 6; ++k) { c1.s[k] = nullptr; c1.d[k] = 0; c1.base[k] = 0x7fffffff; }
    c1.total = acc; c1.special = -1;
  }
  CastArgs c2;
  {
    const float* s6[6] = {W1, W2, comb_W, vocab_W, Wg_W, ptr_W};
    __hip_bfloat16* d6[6] = {w1_16, w2_16, combw16, vocw16, wgw16, ptrw16};
    int ns[6] = {512 * 512, 512 * 1024, 512 * 1536, 8000 * 512, 512 * 512, 128 * 512};
    int acc = 0;
    for (int k = 0; k < 6; ++k) {
      c2.s[k] = s6[k]; c2.d[k] = (unsigned long long)d6[k]; c2.base[k] = acc;
      acc += ns[k];
    }
    c2.total = acc; c2.special = 5;
  }

  // 1) prologue: embed + hbuf sentinel memset + cast1
  prologue_kernel<<<544, 256, 0, stream>>>(src_ids, emb, xb, hbuf, c1);

  // 2) xproj (normal row-major layout)
  xproj_kernel<<<dim3(16, 16, 3), 256, 0, stream>>>(xb, wih16, b_f, b_b, b_d, xproj16);

  // 3) fused lstm + cast2
  hipError_t e1 = hipFuncSetAttribute((const void*)fused_kernel,
                      hipFuncAttributeMaxDynamicSharedMemorySize, 147968);
  (void)e1;
  fused_kernel<<<160, 256, 147968, stream>>>(
      xproj16, Whh_f, Whh_b, Whh_d, hbuf, ehsb, ehsT, catb, c2);

  // 4) dterm + etT merged
  qk_kernel<<<512, 256, 0, stream>>>(catb, ehsb, w1_16, w2_16, dterm, etT);

  // 5) score + softmax
  score_kernel<<<16 * 32, 256, 0, stream>>>(dterm, etT, v_att, src_mask, alphab);

  // 6) context
  ctx_kernel<<<dim3(16, 2, 16), 256, 0, stream>>>(alphab, ehsT, catb + 512);

  // 7) combined
  comb_kernel<<<dim3(8, 32), 256, 0, stream>>>(catb, combw16, comb_b, combb);

  // 8) vocab (+cmask) and wg/base merged
  tail_kernel<<<1328, 256, 0, stream>>>(combb, vocw16, vocab_b, out1, cmask,
                                        wgw16, Wg_b, ptr_b, wgout, baseb);

  // 9) pointer head
  pointer_kernel<<<BN_, 256, 0, stream>>>(baseb, wgout, ptr_W, ps_W, ps_b, src_mask, out0);
}